// Round 16
// baseline (840.760 us; speedup 1.0000x reference)
//
#include <hip/hip_runtime.h>
#include <hip/hip_bf16.h>

#define B_ 8
#define N_ 1024
#define K_ 20
#define BN_ (B_*N_)

#define BN_SCALE 0.9999950000374997f

typedef __attribute__((ext_vector_type(8))) short short8;
typedef __attribute__((ext_vector_type(4))) float f32x4;

__device__ __forceinline__ float US2F(unsigned short u) {
    union { unsigned u; float f; } c; c.u = ((unsigned)u) << 16; return c.f;
}
__device__ __forceinline__ unsigned short F2BF(float f) {   // RNE fp32->bf16
    union { float f; unsigned u; } c; c.f = f;
    unsigned r = c.u + 0x7FFF + ((c.u >> 16) & 1);
    return (unsigned short)(r >> 16);
}

// ---------------------------------------------------------------- dtype detect
__global__ void k_detect(const unsigned short* g1, const unsigned short* g2,
                         const unsigned short* g3, const unsigned short* g4,
                         const unsigned short* g5, const unsigned short* g6,
                         const unsigned short* g7, int* flag) {
    const unsigned short* gs[7] = {g1, g2, g3, g4, g5, g6, g7};
    int cnt = 0;
    for (int i = 0; i < 7; i++) {
        float v = US2F(gs[i][0]);
        if (v > 0.5f && v < 1.5f) cnt++;
    }
    *flag = (cnt >= 4) ? 1 : 0;   // 1 = bf16 inputs, 0 = fp32 inputs
}

// ---------------------------------------------------------------- prep
// mode 0: fp32 transpose (O,I)->(I,O).  mode 2: bf16 copy (keeps (n,k)).
// mode 3: edge pair -> bf16 (2O, C): rows [0,O)=wn, [O,2O)=wc.
struct TPar { const void* src; void* dst; int O, I, blk0, mode; };
struct TList { TPar p[44]; };

__global__ __launch_bounds__(256) void k_prep(TList tl, int nent, const int* flag) {
    const int isbf = *flag;
    int blk = blockIdx.x;
    int wi = 0;
    for (int j = nent - 1; j >= 0; j--) { if (blk >= tl.p[j].blk0) { wi = j; break; } }
    const TPar p = tl.p[wi];
    int e = (blk - p.blk0) * 256 + threadIdx.x;
    int n = p.O * p.I;
    if (e >= n) return;
    int o = e / p.I, i = e - o * p.I;
    float v = isbf ? US2F(((const unsigned short*)p.src)[e])
                   : ((const float*)p.src)[e];
    if (p.mode == 0) {
        ((float*)p.dst)[(size_t)i * p.O + o] = v;
    } else if (p.mode == 2) {
        ((unsigned short*)p.dst)[e] = F2BF(v);
    } else {
        const int C = p.I >> 1;
        if (i < C) ((unsigned short*)p.dst)[(size_t)o * C + i] = F2BF(v);
        else       ((unsigned short*)p.dst)[(size_t)(p.O + o) * C + (i - C)] = F2BF(v);
    }
}

// ---------------------------------------------------------------- norms
__global__ __launch_bounds__(256) void k_norms(const float* __restrict__ xf,
                                               float* __restrict__ xx, int C) {
    int i = blockIdx.x * 256 + threadIdx.x;
    if (i >= BN_) return;
    const float* p = xf + (size_t)i * C;
    float s = 0.f;
    for (int c = 0; c < C; c++) s += p[c] * p[c];
    xx[i] = s;
}

// ---------------------------------------------------------------- kNN phase 1 (fp32: selection must not flip)
// pd[i][j] = 2*dot(x_i,x_j) - xx_j.  128x64 tile, 8x4/thread: 32 FMAs per
// 3 b128 LDS reads (the R15 4x4 tile sat at VALUBusy 32%).
template<int C>
__global__ __launch_bounds__(256) void k_pd(const float* __restrict__ xf,
                                            const float* __restrict__ xx,
                                            float* __restrict__ pd) {
    const int b = blockIdx.z;
    const int rb = blockIdx.x * 128, cb = blockIdx.y * 64;
    const float* xb = xf + (size_t)b * N_ * C;
    const float* xxb = xx + (size_t)b * N_;
    const int t = threadIdx.x;
    __shared__ float As[32][129];   // As[k][m], 129 % 32 == 1 -> conflict-free staging
    __shared__ float Bs[32][65];    // Bs[k][j]
    float acc[8][4] = {};
    const int tm = (t >> 4) * 8, tn = (t & 15) * 4;
    for (int k0 = 0; k0 < C; k0 += 32) {
        __syncthreads();
        #pragma unroll
        for (int u = t; u < 128 * 32; u += 256) {
            int m = u >> 5, k = u & 31;
            float v;
            if constexpr (C % 32 == 0) v = xb[(size_t)(rb + m) * C + k0 + k];
            else v = (k0 + k < C) ? xb[(size_t)(rb + m) * C + k0 + k] : 0.f;
            As[k][m] = v;
        }
        #pragma unroll
        for (int u = t; u < 64 * 32; u += 256) {
            int j = u >> 5, k = u & 31;
            float v;
            if constexpr (C % 32 == 0) v = xb[(size_t)(cb + j) * C + k0 + k];
            else v = (k0 + k < C) ? xb[(size_t)(cb + j) * C + k0 + k] : 0.f;
            Bs[k][j] = v;
        }
        __syncthreads();
        #pragma unroll
        for (int k = 0; k < 32; k++) {
            const float4 a0 = *reinterpret_cast<const float4*>(&As[k][tm]);
            const float4 a1 = *reinterpret_cast<const float4*>(&As[k][tm + 4]);
            const float4 bv = *reinterpret_cast<const float4*>(&Bs[k][tn]);
            const float av[8] = {a0.x, a0.y, a0.z, a0.w, a1.x, a1.y, a1.z, a1.w};
            #pragma unroll
            for (int j = 0; j < 8; j++) {
                acc[j][0] += av[j] * bv.x; acc[j][1] += av[j] * bv.y;
                acc[j][2] += av[j] * bv.z; acc[j][3] += av[j] * bv.w;
            }
        }
    }
    float* pdb = pd + (size_t)b * N_ * N_;
    #pragma unroll
    for (int j = 0; j < 8; j++) {
        const int row = rb + tm + j;
        #pragma unroll
        for (int jj = 0; jj < 4; jj++)
            pdb[(size_t)row * N_ + cb + tn + jj] = 2.f * acc[j][jj] - xxb[cb + tn + jj];
    }
}

// ---------------------------------------------------------------- kNN phase 2
// u64-key top-20: key = (ordered_float_bits << 32) | (1023 - j).
__global__ __launch_bounds__(256) void k_sel(const float* __restrict__ pd,
                                             int* __restrict__ idx) {
    const int w = threadIdx.x >> 6, lane = threadIdx.x & 63;
    const int i = blockIdx.x * 4 + w;          // 0..8191
    const int b = i >> 10;
    const float* row = pd + (size_t)b * N_ * N_ + (size_t)(i & 1023) * N_;
    unsigned long long key[16];
    #pragma unroll
    for (int q = 0; q < 16; q++) {
        const int j = q * 64 + lane;
        unsigned bits = __float_as_uint(row[j]);
        bits = (bits & 0x80000000u) ? ~bits : (bits | 0x80000000u);
        key[q] = ((unsigned long long)bits << 32) | (unsigned)(N_ - 1 - j);
    }
    int myj = 0;
    for (int kk = 0; kk < K_; kk++) {
        unsigned long long m = key[0];
        #pragma unroll
        for (int u = 1; u < 16; u++) m = key[u] > m ? key[u] : m;
        #pragma unroll
        for (int s = 1; s < 64; s <<= 1) {
            unsigned long long o = (unsigned long long)__shfl_xor((long long)m, s, 64);
            m = o > m ? o : m;
        }
        const int j = N_ - 1 - (int)(m & 0xFFFFFFFFull);
        if (lane == kk) myj = j;
        #pragma unroll
        for (int u = 0; u < 16; u++)
            if (key[u] == m) key[u] = 0ULL;    // 0 < any real key
    }
    if (lane < K_) idx[(size_t)i * K_ + lane] = myj;
}

// ---------------------------------------------------------------- MFMA bf16 GEMM
// C[8192][NC] = A[8192][KD] @ Bw^T; A (8192,KD) bf16, Bw (NC,KD) bf16 (n,k).
// Tile TM x TN (64/128): 4 waves in 2x2 quadrants of (TM/2 x TN/2), each
// (TM/32)x(TN/32) mfma_f32_16x16x32_bf16. Staging = pure b128 copies.
template<int KD, int NC, int TM, int TN>
__global__ __launch_bounds__(256) void k_gemmb(const unsigned short* __restrict__ A,
                                               const unsigned short* __restrict__ Bw,
                                               const float* __restrict__ bias,
                                               const float* __restrict__ resid,
                                               float* __restrict__ Cout,
                                               int scale_cols, float qs,
                                               const float* __restrict__ gamma,
                                               const float* __restrict__ beta,
                                               unsigned short* __restrict__ obf) {
    const int t = threadIdx.x;
    const int rb = blockIdx.x * TM, cb = blockIdx.y * TN;
    __shared__ __align__(16) unsigned short As[TM * 40];
    __shared__ __align__(16) unsigned short Bs[TN * 40];
    const int w = t >> 6, lane = t & 63;
    constexpr int QR = TM / 2, QC = TN / 2;
    constexpr int MR = QR / 16, NR = QC / 16;
    const int wr = (w & 1) * QR, wc = (w >> 1) * QC;
    const int fr = lane & 15, fq = (lane >> 4) * 8;
    f32x4 acc[MR][NR] = {};
    for (int k0 = 0; k0 < KD; k0 += 32) {
        __syncthreads();
        #pragma unroll
        for (int u = t; u < TM * 4; u += 256) {
            const int m = u >> 2, c = (u & 3) * 8;
            if constexpr (KD % 32 == 0) {
                *reinterpret_cast<short8*>(&As[m * 40 + c]) =
                    *reinterpret_cast<const short8*>(&A[(size_t)(rb + m) * KD + k0 + c]);
            } else {
                #pragma unroll
                for (int j = 0; j < 8; j++) {
                    const int kk = k0 + c + j;
                    As[m * 40 + c + j] = (kk < KD) ? A[(size_t)(rb + m) * KD + kk] : (unsigned short)0;
                }
            }
        }
        #pragma unroll
        for (int u = t; u < TN * 4; u += 256) {
            const int n = u >> 2, c = (u & 3) * 8;
            const int gn = cb + n;
            if (gn < NC) {
                if constexpr (KD % 32 == 0) {
                    *reinterpret_cast<short8*>(&Bs[n * 40 + c]) =
                        *reinterpret_cast<const short8*>(&Bw[(size_t)gn * KD + k0 + c]);
                } else {
                    #pragma unroll
                    for (int j = 0; j < 8; j++) {
                        const int kk = k0 + c + j;
                        Bs[n * 40 + c + j] = (kk < KD) ? Bw[(size_t)gn * KD + kk] : (unsigned short)0;
                    }
                }
            } else {
                short8 z = {};
                *reinterpret_cast<short8*>(&Bs[n * 40 + c]) = z;
            }
        }
        __syncthreads();
        short8 af[MR], bfr[NR];
        #pragma unroll
        for (int mi = 0; mi < MR; mi++)
            af[mi] = *reinterpret_cast<const short8*>(&As[(wr + mi * 16 + fr) * 40 + fq]);
        #pragma unroll
        for (int ni = 0; ni < NR; ni++)
            bfr[ni] = *reinterpret_cast<const short8*>(&Bs[(wc + ni * 16 + fr) * 40 + fq]);
        #pragma unroll
        for (int mi = 0; mi < MR; mi++) {
            #pragma unroll
            for (int ni = 0; ni < NR; ni++)
                acc[mi][ni] = __builtin_amdgcn_mfma_f32_16x16x32_bf16(af[mi], bfr[ni], acc[mi][ni], 0, 0, 0);
        }
    }
    const int cr = (lane >> 4) * 4, cc = lane & 15;
    #pragma unroll
    for (int mi = 0; mi < MR; mi++) {
        #pragma unroll
        for (int ni = 0; ni < NR; ni++) {
            #pragma unroll
            for (int r = 0; r < 4; r++) {
                const int row = rb + wr + mi * 16 + cr + r;
                const int col = cb + wc + ni * 16 + cc;
                if (col < NC) {
                    float v = acc[mi][ni][r] + (bias ? bias[col] : 0.f);
                    if (col < scale_cols) v *= qs;
                    if (resid) v += resid[(size_t)row * NC + col];
                    if (gamma) {
                        v = v * (gamma[col] * BN_SCALE) + beta[col];
                        v = v >= 0.f ? v : 0.2f * v;
                    }
                    Cout[(size_t)row * NC + col] = v;
                    if (obf) obf[(size_t)row * NC + col] = F2BF(v);
                }
            }
        }
    }
}

// ---------------------------------------------------------------- EdgeConv epilogue (fp32 out + bf16 copy)
template<int CO>
__global__ __launch_bounds__(256) void k_edgemax(const float* __restrict__ yz,
                                                 const int* __restrict__ idx,
                                                 const float* __restrict__ g,
                                                 const float* __restrict__ bb,
                                                 float* __restrict__ out,
                                                 unsigned short* __restrict__ outb) {
    constexpr int TPP = CO / 4;
    constexpr int PPB = 256 / TPP;
    const int t = threadIdx.x;
    const int p = t / TPP;
    const int cw = (t % TPP) * 4;
    const int i0 = blockIdx.x * PPB;
    const int bbase = (i0 >> 10) << 10;
    __shared__ int sidx[PPB][K_];
    for (int u = t; u < PPB * K_; u += 256) {
        int pp = u / K_, kk = u - pp * K_;
        sidx[pp][kk] = idx[(size_t)(i0 + pp) * K_ + kk];
    }
    __syncthreads();
    const int ig = i0 + p;
    float4 m = {-3e38f, -3e38f, -3e38f, -3e38f};
    #pragma unroll 4
    for (int k = 0; k < K_; k++) {
        const int jg = bbase + sidx[p][k];
        const float4 yv = *reinterpret_cast<const float4*>(&yz[(size_t)jg * 2 * CO + cw]);
        m.x = fmaxf(m.x, yv.x); m.y = fmaxf(m.y, yv.y);
        m.z = fmaxf(m.z, yv.z); m.w = fmaxf(m.w, yv.w);
    }
    const float4 yi = *reinterpret_cast<const float4*>(&yz[(size_t)ig * 2 * CO + cw]);
    const float4 zi = *reinterpret_cast<const float4*>(&yz[(size_t)ig * 2 * CO + CO + cw]);
    const float4 gv = *reinterpret_cast<const float4*>(&g[cw]);
    const float4 bv = *reinterpret_cast<const float4*>(&bb[cw]);
    float vals[4] = {m.x - yi.x + zi.x, m.y - yi.y + zi.y,
                     m.z - yi.z + zi.z, m.w - yi.w + zi.w};
    float gs[4] = {gv.x, gv.y, gv.z, gv.w};
    float bs[4] = {bv.x, bv.y, bv.z, bv.w};
    float4 o;
    float* op = &o.x;
    #pragma unroll
    for (int j = 0; j < 4; j++) {
        float h = vals[j] * (gs[j] * BN_SCALE) + bs[j];
        op[j] = h >= 0.f ? h : 0.2f * h;
    }
    *reinterpret_cast<float4*>(&out[(size_t)ig * CO + cw]) = o;
    #pragma unroll
    for (int j = 0; j < 4; j++) outb[(size_t)ig * CO + cw + j] = F2BF(op[j]);
}

// ---------------------------------------------------------------- attention (fp32 math, bf16 out)
template<int E>
__global__ __launch_bounds__(256) void k_attn(const float* __restrict__ qkv,
                                              unsigned short* __restrict__ o) {
    constexpr int H = 4, D = E / H, L = 8;
    const int n = blockIdx.x;
    const int t = threadIdx.x;
    const int h = t >> 6, lane = t & 63;
    __shared__ float sq[L][3 * E];
    __shared__ float so[L][E];
    for (int u = t; u < L * 3 * E; u += 256) {
        int l = u / (3 * E), r = u - l * (3 * E);
        sq[l][r] = qkv[(size_t)(l * N_ + n) * (3 * E) + r];
    }
    __syncthreads();
    const int l = lane >> 3, m = lane & 7;
    float s = 0.f;
    #pragma unroll 8
    for (int dd = 0; dd < D; dd++)
        s += sq[l][h * D + dd] * sq[m][E + h * D + dd];
    float mx = s;
    #pragma unroll
    for (int st = 1; st < 8; st <<= 1) mx = fmaxf(mx, __shfl_xor(mx, st, 64));
    float e = expf(s - mx);
    float sum = e;
    #pragma unroll
    for (int st = 1; st < 8; st <<= 1) sum += __shfl_xor(sum, st, 64);
    const float p = e / sum;
    float pm[8];
    #pragma unroll
    for (int mm = 0; mm < 8; mm++) pm[mm] = __shfl(p, (lane & 56) | mm, 64);
    #pragma unroll
    for (int j = 0; j < D / 8; j++) {
        const int dd = m + 8 * j;
        float a = 0.f;
        #pragma unroll
        for (int mm = 0; mm < 8; mm++) a += pm[mm] * sq[mm][2 * E + h * D + dd];
        so[l][h * D + dd] = a;
    }
    __syncthreads();
    for (int u = t; u < L * E; u += 256) {
        int l2 = u / E, e2 = u - l2 * E;
        o[(size_t)(l2 * N_ + n) * E + e2] = F2BF(so[l2][e2]);
    }
}

// ---------------------------------------------------------------- cat (bf16 -> bf16)
__global__ __launch_bounds__(256) void k_cat(const unsigned short* __restrict__ x1, const unsigned short* __restrict__ x2,
                                             const unsigned short* __restrict__ x3, const unsigned short* __restrict__ x4,
                                             unsigned short* __restrict__ cat) {
    int u = blockIdx.x * 256 + threadIdx.x;
    int p = u >> 9, c = u & 511;
    unsigned short v;
    if (c < 64)       v = x1[(size_t)p * 64 + c];
    else if (c < 128) v = x2[(size_t)p * 64 + (c - 64)];
    else if (c < 256) v = x3[(size_t)p * 128 + (c - 128)];
    else              v = x4[(size_t)p * 256 + (c - 256)];
    cat[u] = v;
}

// ---------------------------------------------------------------- pool (two-phase)
__global__ __launch_bounds__(256) void k_pool1(const float* __restrict__ h5,
                                               float* __restrict__ pmax,
                                               float* __restrict__ psum) {
    int c = blockIdx.x * 256 + threadIdx.x;
    int b = blockIdx.y, ch = blockIdx.z;
    float mx = -3e38f, sm = 0.f;
    for (int n = ch * 128; n < ch * 128 + 128; n++) {
        float v = h5[((size_t)b * N_ + n) * 1024 + c];
        mx = fmaxf(mx, v); sm += v;
    }
    pmax[((size_t)b * 8 + ch) * 1024 + c] = mx;
    psum[((size_t)b * 8 + ch) * 1024 + c] = sm;
}

__global__ __launch_bounds__(256) void k_pool2(const float* __restrict__ pmax,
                                               const float* __restrict__ psum,
                                               float* __restrict__ feat) {
    int c = blockIdx.x * 256 + threadIdx.x;
    int b = blockIdx.y;
    float mx = -3e38f, sm = 0.f;
    #pragma unroll
    for (int ch = 0; ch < 8; ch++) {
        mx = fmaxf(mx, pmax[((size_t)b * 8 + ch) * 1024 + c]);
        sm += psum[((size_t)b * 8 + ch) * 1024 + c];
    }
    feat[b * 2048 + c] = mx;
    feat[b * 2048 + 1024 + c] = sm * (1.f / 1024.f);
}

// ---------------------------------------------------------------- FC head
__global__ __launch_bounds__(256) void k_fc1(const float* __restrict__ feat, const float* __restrict__ l1wT,
                                             const float* __restrict__ g6, const float* __restrict__ b6,
                                             float* __restrict__ f1) {
    int oc = blockIdx.x, b = blockIdx.y, t = threadIdx.x;
    __shared__ float fin[2048];
    __shared__ float psum[4][64];
    for (int u = t; u < 2048; u += 256) fin[u] = feat[b * 2048 + u];
    __syncthreads();
    int ol = t & 63, kc = t >> 6;
    int o = oc * 64 + ol;
    float acc = 0.f;
    for (int c = kc * 512; c < kc * 512 + 512; c++) acc += fin[c] * l1wT[(size_t)c * 512 + o];
    psum[kc][ol] = acc;
    __syncthreads();
    if (t < 64) {
        int oo = oc * 64 + t;
        float a = psum[0][t] + psum[1][t] + psum[2][t] + psum[3][t];
        float h = a * (g6[oo] * BN_SCALE) + b6[oo];
        f1[b * 512 + oo] = h >= 0.f ? h : 0.2f * h;
    }
}

__global__ __launch_bounds__(256) void k_fc2(const float* __restrict__ f1, const float* __restrict__ l2wT,
                                             const float* __restrict__ l2b,
                                             const float* __restrict__ g7, const float* __restrict__ b7,
                                             float* __restrict__ f2) {
    int b = blockIdx.x, t = threadIdx.x;
    __shared__ float fin[512];
    for (int u = t; u < 512; u += 256) fin[u] = f1[b * 512 + u];
    __syncthreads();
    if (t < 256) {
        int o = t;
        float acc = 0.f;
        for (int c = 0; c < 512; c++) acc += fin[c] * l2wT[(size_t)c * 256 + o];
        acc += l2b[o];
        float h = acc * (g7[o] * BN_SCALE) + b7[o];
        f2[b * 256 + o] = h >= 0.f ? h : 0.2f * h;
    }
}

__global__ __launch_bounds__(64) void k_fc3(const float* __restrict__ f2, const float* __restrict__ l3wT,
                                            const float* __restrict__ l3b,
                                            void* __restrict__ out, const int* __restrict__ flag) {
    int b = blockIdx.x, t = threadIdx.x;
    __shared__ float fin[256];
    for (int u = t; u < 256; u += 64) fin[u] = f2[b * 256 + u];
    __syncthreads();
    if (t < 40) {
        float acc = 0.f;
        for (int c = 0; c < 256; c++) acc += fin[c] * l3wT[(size_t)c * 40 + t];
        acc += l3b[t];
        if (*flag) ((__hip_bfloat16*)out)[b * 40 + t] = __float2bfloat16(acc);
        else       ((float*)out)[b * 40 + t] = acc;
    }
}

// ================================================================ host
extern "C" void kernel_launch(void* const* d_in, const int* in_sizes, int n_in,
                              void* d_out, int out_size, void* d_ws, size_t ws_size,
                              hipStream_t stream) {
    auto us = [&](int i) { return (const unsigned short*)d_in[i]; };

    float* ws = (float*)d_ws;
    size_t off = 0;
    auto A = [&](size_t n) { float* p = ws + off; off += (n + 3) & ~(size_t)3; return p; };
    auto AU = [&](size_t n) { return (unsigned short*)A((n + 1) / 2); };
    float* xf0  = A((size_t)BN_ * 3);
    float* x1   = A((size_t)BN_ * 64);
    float* x2   = A((size_t)BN_ * 64);
    float* x3   = A((size_t)BN_ * 128);
    float* x4   = A((size_t)BN_ * 256);
    float* h5   = A((size_t)BN_ * 1024);   // also pd scratch
    float* feat = A(8 * 2048);
    float* f1   = A(8 * 512);
    float* f2   = A(8 * 256);
    float* xx   = A(BN_);
    int*   idx  = (int*)A((size_t)BN_ * K_);
    int*   flag = (int*)A(4);
    float* qkvw = A((size_t)BN_ * 768);   // qkv / yz scratch (fp32)
    // bf16 activation copies
    unsigned short* xf0b = AU((size_t)BN_ * 3);
    unsigned short* x1b  = AU((size_t)BN_ * 64);
    unsigned short* x2b  = AU((size_t)BN_ * 64);
    unsigned short* x3b  = AU((size_t)BN_ * 128);
    unsigned short* x4b  = AU((size_t)BN_ * 256);
    unsigned short* owb  = AU((size_t)BN_ * 256);
    unsigned short* catb = AU((size_t)BN_ * 512);
    float* pmax = A(8 * 8 * 1024);
    float* psum = A(8 * 8 * 1024);
    // bf16 weights (n,k) layouts
    unsigned short* w1yzb = AU(128 * 3);
    unsigned short* w2yzb = AU(128 * 64);
    unsigned short* w3yzb = AU(256 * 64);
    unsigned short* w4yzb = AU(512 * 128);
    unsigned short* a1wib = AU(192 * 64);  unsigned short* a1wob = AU(64 * 64);
    unsigned short* a2wib = AU(192 * 64);  unsigned short* a2wob = AU(64 * 64);
    unsigned short* a3wib = AU(384 * 128); unsigned short* a3wob = AU(128 * 128);
    unsigned short* a4wib = AU(768 * 256); unsigned short* a4wob = AU(256 * 256);
    unsigned short* w5b   = AU(1024 * 512);
    // fp32 fc weights (transposed)
    float* l1wT  = A(2048 * 512);
    float* l2wT  = A(512 * 256);
    float* l3wT  = A(256 * 40);
    // converted vectors (fp32)
    float* g1f = A(64);   float* b1f = A(64);
    float* g2f = A(64);   float* b2f = A(64);
    float* g3f = A(128);  float* b3f = A(128);
    float* g4f = A(256);  float* b4f = A(256);
    float* bi1 = A(192);  float* bo1 = A(64);
    float* bi2 = A(192);  float* bo2 = A(64);
    float* bi3 = A(384);  float* bo3 = A(128);
    float* bi4 = A(768);  float* bo4 = A(256);
    float* g5f = A(1024); float* b5f = A(1024);
    float* g6f = A(512);  float* b6f = A(512);
    float* l2bf = A(256);
    float* g7f = A(256);  float* b7f = A(256);
    float* l3bf = A(40);

    k_detect<<<1, 1, 0, stream>>>(us(2), us(5), us(8), us(11), us(30), us(33), us(37), flag);

    TList tl; int nb = 0; int k = 0;
    auto add = [&](int i, void* dst, int O, int I, int mode) {
        tl.p[k].src = d_in[i]; tl.p[k].dst = dst; tl.p[k].O = O; tl.p[k].I = I;
        tl.p[k].blk0 = nb; tl.p[k].mode = mode;
        nb += (O * I + 255) / 256; k++;
    };
    add(0,  xf0,   BN_ * 3, 1, 0);
    add(0,  xf0b,  BN_ * 3, 1, 2);
    add(1,  w1yzb, 64, 6, 3);
    add(4,  w2yzb, 64, 128, 3);
    add(7,  w3yzb, 128, 128, 3);
    add(10, w4yzb, 256, 256, 3);
    add(13, a1wib, 192, 64, 2);
    add(15, a1wob, 64, 64, 2);
    add(17, a2wib, 192, 64, 2);
    add(19, a2wob, 64, 64, 2);
    add(21, a3wib, 384, 128, 2);
    add(23, a3wob, 128, 128, 2);
    add(25, a4wib, 768, 256, 2);
    add(27, a4wob, 256, 256, 2);
    add(29, w5b,   1024, 512, 2);
    add(32, l1wT,  512, 2048, 0);
    add(35, l2wT,  256, 512, 0);
    add(39, l3wT,  40, 256, 0);
    add(2,  g1f, 64, 1, 0);   add(3,  b1f, 64, 1, 0);
    add(5,  g2f, 64, 1, 0);   add(6,  b2f, 64, 1, 0);
    add(8,  g3f, 128, 1, 0);  add(9,  b3f, 128, 1, 0);
    add(11, g4f, 256, 1, 0);  add(12, b4f, 256, 1, 0);
    add(14, bi1, 192, 1, 0);  add(16, bo1, 64, 1, 0);
    add(18, bi2, 192, 1, 0);  add(20, bo2, 64, 1, 0);
    add(22, bi3, 384, 1, 0);  add(24, bo3, 128, 1, 0);
    add(26, bi4, 768, 1, 0);  add(28, bo4, 256, 1, 0);
    add(30, g5f, 1024, 1, 0); add(31, b5f, 1024, 1, 0);
    add(33, g6f, 512, 1, 0);  add(34, b6f, 512, 1, 0);
    add(36, l2bf, 256, 1, 0);
    add(37, g7f, 256, 1, 0);  add(38, b7f, 256, 1, 0);
    add(40, l3bf, 40, 1, 0);
    k_prep<<<nb, 256, 0, stream>>>(tl, k, flag);

    float* yzb = qkvw;                 // fp32 yz scratch
    float* pd  = h5;                   // pd scratch (h5 dead until conv5)
    const dim3 pdg(8, 16, 8);          // 128-row x 64-col tiles

    // layer 1  (C=3 -> 64)
    k_norms<<<BN_ / 256, 256, 0, stream>>>(xf0, xx, 3);
    k_pd<3><<<pdg, 256, 0, stream>>>(xf0, xx, pd);
    k_sel<<<BN_ / 4, 256, 0, stream>>>(pd, idx);
    k_gemmb<3, 128, 64, 64><<<dim3(128, 2), 256, 0, stream>>>(xf0b, w1yzb, nullptr, nullptr, yzb, 0, 1.f, nullptr, nullptr, nullptr);
    k_edgemax<64><<<BN_ / 16, 256, 0, stream>>>(yzb, idx, g1f, b1f, x1, x1b);
    k_gemmb<64, 192, 64, 64><<<dim3(128, 3), 256, 0, stream>>>(x1b, a1wib, bi1, nullptr, qkvw, 64, 0.25f, nullptr, nullptr, nullptr);
    k_attn<64><<<N_, 256, 0, stream>>>(qkvw, owb);
    k_gemmb<64, 64, 64, 64><<<dim3(128, 1), 256, 0, stream>>>(owb, a1wob, bo1, x1, x1, 0, 1.f, nullptr, nullptr, x1b);

    // layer 2  (C=64 -> 64)
    k_norms<<<BN_ / 256, 256, 0, stream>>>(x1, xx, 64);
    k_pd<64><<<pdg, 256, 0, stream>>>(x1, xx, pd);
    k_sel<<<BN_ / 4, 256, 0, stream>>>(pd, idx);
    k_gemmb<64, 128, 64, 64><<<dim3(128, 2), 256, 0, stream>>>(x1b, w2yzb, nullptr, nullptr, yzb, 0, 1.f, nullptr, nullptr, nullptr);
    k_edgemax<64><<<BN_ / 16, 256, 0, stream>>>(yzb, idx, g2f, b2f, x2, x2b);
    k_gemmb<64, 192, 64, 64><<<dim3(128, 3), 256, 0, stream>>>(x2b, a2wib, bi2, nullptr, qkvw, 64, 0.25f, nullptr, nullptr, nullptr);
    k_attn<64><<<N_, 256, 0, stream>>>(qkvw, owb);
    k_gemmb<64, 64, 64, 64><<<dim3(128, 1), 256, 0, stream>>>(owb, a2wob, bo2, x2, x2, 0, 1.f, nullptr, nullptr, x2b);

    // layer 3  (C=64 -> 128)
    k_norms<<<BN_ / 256, 256, 0, stream>>>(x2, xx, 64);
    k_pd<64><<<pdg, 256, 0, stream>>>(x2, xx, pd);
    k_sel<<<BN_ / 4, 256, 0, stream>>>(pd, idx);
    k_gemmb<64, 256, 64, 64><<<dim3(128, 4), 256, 0, stream>>>(x2b, w3yzb, nullptr, nullptr, yzb, 0, 1.f, nullptr, nullptr, nullptr);
    k_edgemax<128><<<BN_ / 8, 256, 0, stream>>>(yzb, idx, g3f, b3f, x3, x3b);
    k_gemmb<128, 384, 64, 128><<<dim3(128, 3), 256, 0, stream>>>(x3b, a3wib, bi3, nullptr, qkvw, 128, 0.17677669529663687f, nullptr, nullptr, nullptr);
    k_attn<128><<<N_, 256, 0, stream>>>(qkvw, owb);
    k_gemmb<128, 128, 64, 64><<<dim3(128, 2), 256, 0, stream>>>(owb, a3wob, bo3, x3, x3, 0, 1.f, nullptr, nullptr, x3b);

    // layer 4  (C=128 -> 256)
    k_norms<<<BN_ / 256, 256, 0, stream>>>(x3, xx, 128);
    k_pd<128><<<pdg, 256, 0, stream>>>(x3, xx, pd);
    k_sel<<<BN_ / 4, 256, 0, stream>>>(pd, idx);
    k_gemmb<128, 512, 128, 128><<<dim3(64, 4), 256, 0, stream>>>(x3b, w4yzb, nullptr, nullptr, yzb, 0, 1.f, nullptr, nullptr, nullptr);
    k_edgemax<256><<<BN_ / 4, 256, 0, stream>>>(yzb, idx, g4f, b4f, x4, x4b);
    k_gemmb<256, 768, 128, 128><<<dim3(64, 6), 256, 0, stream>>>(x4b, a4wib, bi4, nullptr, qkvw, 256, 0.125f, nullptr, nullptr, nullptr);
    k_attn<256><<<N_, 256, 0, stream>>>(qkvw, owb);
    k_gemmb<256, 256, 64, 128><<<dim3(128, 2), 256, 0, stream>>>(owb, a4wob, bo4, x4, x4, 0, 1.f, nullptr, nullptr, x4b);

    // head
    k_cat<<<(BN_ * 512) / 256, 256, 0, stream>>>(x1b, x2b, x3b, x4b, catb);
    k_gemmb<512, 1024, 128, 128><<<dim3(64, 8), 256, 0, stream>>>(catb, w5b, nullptr, nullptr, h5, 0, 1.f, g5f, b5f, nullptr);
    k_pool1<<<dim3(4, 8, 8), 256, 0, stream>>>(h5, pmax, psum);
    k_pool2<<<dim3(4, 8), 256, 0, stream>>>(pmax, psum, feat);
    k_fc1<<<dim3(8, 8), 256, 0, stream>>>(feat, l1wT, g6f, b6f, f1);
    k_fc2<<<8, 256, 0, stream>>>(f1, l2wT, l2bf, g7f, b7f, f2);
    k_fc3<<<8, 64, 0, stream>>>(f2, l3wT, l3bf, d_out, flag);
}

// Round 17
// 774.277 us; speedup vs baseline: 1.0859x; 1.0859x over previous
//
#include <hip/hip_runtime.h>
#include <hip/hip_bf16.h>

#define B_ 8
#define N_ 1024
#define K_ 20
#define BN_ (B_*N_)

#define BN_SCALE 0.9999950000374997f

typedef __attribute__((ext_vector_type(8))) short short8;
typedef __attribute__((ext_vector_type(4))) float f32x4;

__device__ __forceinline__ float US2F(unsigned short u) {
    union { unsigned u; float f; } c; c.u = ((unsigned)u) << 16; return c.f;
}
__device__ __forceinline__ unsigned short F2BF(float f) {   // RNE fp32->bf16
    union { float f; unsigned u; } c; c.f = f;
    unsigned r = c.u + 0x7FFF + ((c.u >> 16) & 1);
    return (unsigned short)(r >> 16);
}

// ---------------------------------------------------------------- dtype detect
__global__ void k_detect(const unsigned short* g1, const unsigned short* g2,
                         const unsigned short* g3, const unsigned short* g4,
                         const unsigned short* g5, const unsigned short* g6,
                         const unsigned short* g7, int* flag) {
    const unsigned short* gs[7] = {g1, g2, g3, g4, g5, g6, g7};
    int cnt = 0;
    for (int i = 0; i < 7; i++) {
        float v = US2F(gs[i][0]);
        if (v > 0.5f && v < 1.5f) cnt++;
    }
    *flag = (cnt >= 4) ? 1 : 0;   // 1 = bf16 inputs, 0 = fp32 inputs
}

// ---------------------------------------------------------------- prep
// mode 0: fp32 transpose (O,I)->(I,O).  mode 2: bf16 copy (keeps (n,k)).
// mode 3: edge pair -> bf16 (2O, C): rows [0,O)=wn, [O,2O)=wc.
struct TPar { const void* src; void* dst; int O, I, blk0, mode; };
struct TList { TPar p[44]; };

__global__ __launch_bounds__(256) void k_prep(TList tl, int nent, const int* flag) {
    const int isbf = *flag;
    int blk = blockIdx.x;
    int wi = 0;
    for (int j = nent - 1; j >= 0; j--) { if (blk >= tl.p[j].blk0) { wi = j; break; } }
    const TPar p = tl.p[wi];
    int e = (blk - p.blk0) * 256 + threadIdx.x;
    int n = p.O * p.I;
    if (e >= n) return;
    int o = e / p.I, i = e - o * p.I;
    float v = isbf ? US2F(((const unsigned short*)p.src)[e])
                   : ((const float*)p.src)[e];
    if (p.mode == 0) {
        ((float*)p.dst)[(size_t)i * p.O + o] = v;
    } else if (p.mode == 2) {
        ((unsigned short*)p.dst)[e] = F2BF(v);
    } else {
        const int C = p.I >> 1;
        if (i < C) ((unsigned short*)p.dst)[(size_t)o * C + i] = F2BF(v);
        else       ((unsigned short*)p.dst)[(size_t)(p.O + o) * C + (i - C)] = F2BF(v);
    }
}

// ---------------------------------------------------------------- norms
__global__ __launch_bounds__(256) void k_norms(const float* __restrict__ xf,
                                               float* __restrict__ xx, int C) {
    int i = blockIdx.x * 256 + threadIdx.x;
    if (i >= BN_) return;
    const float* p = xf + (size_t)i * C;
    float s = 0.f;
    for (int c = 0; c < C; c++) s += p[c] * p[c];
    xx[i] = s;
}

// ---------------------------------------------------------------- kNN split:
// x (fp32) -> augmented bf16 rows (exact-split): xa=[hi,lo,hi,lo],
// xb=[hi,hi,lo,lo], zero-padded to KP.  dot(xa_i, xb_j) over KP =
// (hi+lo)_i . (hi+lo)_j with fp32 MFMA accumulation (error ~2^-17).
template<int C, int KP>
__global__ __launch_bounds__(256) void k_split(const float* __restrict__ x,
                                               unsigned short* __restrict__ xa,
                                               unsigned short* __restrict__ xb) {
    const int e = blockIdx.x * 256 + threadIdx.x;
    if (e >= BN_ * KP) return;
    const int i = e / KP, p = e - i * KP;
    unsigned short va = 0, vb = 0;
    if (p < 4 * C) {
        const int seg = p / C, c = p - seg * C;
        const float v = x[(size_t)i * C + c];
        const unsigned short h = F2BF(v);
        const unsigned short l = F2BF(v - US2F(h));
        va = (seg & 1) ? l : h;           // hi,lo,hi,lo
        vb = (seg < 2) ? h : l;           // hi,hi,lo,lo
    }
    xa[e] = va;
    xb[e] = vb;
}

// ---------------------------------------------------------------- kNN phase 1 (MFMA):
// pd[b][i][j] = 2*dot(xa_i, xb_j) - xx_j.  128x128 tile, 4 waves x 64x64
// quadrant, 4x4 mfma_f32_16x16x32_bf16 (same structure as k_gemmb).
template<int KP>
__global__ __launch_bounds__(256) void k_pdm(const unsigned short* __restrict__ xa,
                                             const unsigned short* __restrict__ xb,
                                             const float* __restrict__ xx,
                                             float* __restrict__ pd) {
    const int b = blockIdx.z;
    const int rb = blockIdx.x * 128, cb = blockIdx.y * 128;
    const unsigned short* Ab = xa + (size_t)b * N_ * KP;
    const unsigned short* Bb = xb + (size_t)b * N_ * KP;
    const float* xxb = xx + (size_t)b * N_;
    const int t = threadIdx.x;
    __shared__ __align__(16) unsigned short As[128 * 40];
    __shared__ __align__(16) unsigned short Bs[128 * 40];
    const int w = t >> 6, lane = t & 63;
    const int wr = (w & 1) * 64, wc = (w >> 1) * 64;
    const int fr = lane & 15, fq = (lane >> 4) * 8;
    f32x4 acc[4][4] = {};
    for (int k0 = 0; k0 < KP; k0 += 32) {
        __syncthreads();
        #pragma unroll
        for (int u = t; u < 512; u += 256) {
            const int m = u >> 2, c = (u & 3) * 8;
            *reinterpret_cast<short8*>(&As[m * 40 + c]) =
                *reinterpret_cast<const short8*>(&Ab[(size_t)(rb + m) * KP + k0 + c]);
        }
        #pragma unroll
        for (int u = t; u < 512; u += 256) {
            const int n = u >> 2, c = (u & 3) * 8;
            *reinterpret_cast<short8*>(&Bs[n * 40 + c]) =
                *reinterpret_cast<const short8*>(&Bb[(size_t)(cb + n) * KP + k0 + c]);
        }
        __syncthreads();
        short8 af[4], bfr[4];
        #pragma unroll
        for (int mi = 0; mi < 4; mi++)
            af[mi] = *reinterpret_cast<const short8*>(&As[(wr + mi * 16 + fr) * 40 + fq]);
        #pragma unroll
        for (int ni = 0; ni < 4; ni++)
            bfr[ni] = *reinterpret_cast<const short8*>(&Bs[(wc + ni * 16 + fr) * 40 + fq]);
        #pragma unroll
        for (int mi = 0; mi < 4; mi++) {
            #pragma unroll
            for (int ni = 0; ni < 4; ni++)
                acc[mi][ni] = __builtin_amdgcn_mfma_f32_16x16x32_bf16(af[mi], bfr[ni], acc[mi][ni], 0, 0, 0);
        }
    }
    float* pdb = pd + (size_t)b * N_ * N_;
    const int cr = (lane >> 4) * 4, cc = lane & 15;
    #pragma unroll
    for (int mi = 0; mi < 4; mi++) {
        #pragma unroll
        for (int ni = 0; ni < 4; ni++) {
            #pragma unroll
            for (int r = 0; r < 4; r++) {
                const int row = rb + wr + mi * 16 + cr + r;
                const int col = cb + wc + ni * 16 + cc;
                pdb[(size_t)row * N_ + col] = 2.f * acc[mi][ni][r] - xxb[col];
            }
        }
    }
}

// ---------------------------------------------------------------- kNN phase 2
// u64-key top-20: key = (ordered_float_bits << 32) | (1023 - j).
__global__ __launch_bounds__(256) void k_sel(const float* __restrict__ pd,
                                             int* __restrict__ idx) {
    const int w = threadIdx.x >> 6, lane = threadIdx.x & 63;
    const int i = blockIdx.x * 4 + w;          // 0..8191
    const int b = i >> 10;
    const float* row = pd + (size_t)b * N_ * N_ + (size_t)(i & 1023) * N_;
    unsigned long long key[16];
    #pragma unroll
    for (int q = 0; q < 16; q++) {
        const int j = q * 64 + lane;
        unsigned bits = __float_as_uint(row[j]);
        bits = (bits & 0x80000000u) ? ~bits : (bits | 0x80000000u);
        key[q] = ((unsigned long long)bits << 32) | (unsigned)(N_ - 1 - j);
    }
    int myj = 0;
    for (int kk = 0; kk < K_; kk++) {
        unsigned long long m = key[0];
        #pragma unroll
        for (int u = 1; u < 16; u++) m = key[u] > m ? key[u] : m;
        #pragma unroll
        for (int s = 1; s < 64; s <<= 1) {
            unsigned long long o = (unsigned long long)__shfl_xor((long long)m, s, 64);
            m = o > m ? o : m;
        }
        const int j = N_ - 1 - (int)(m & 0xFFFFFFFFull);
        if (lane == kk) myj = j;
        #pragma unroll
        for (int u = 0; u < 16; u++)
            if (key[u] == m) key[u] = 0ULL;    // 0 < any real key
    }
    if (lane < K_) idx[(size_t)i * K_ + lane] = myj;
}

// ---------------------------------------------------------------- MFMA bf16 GEMM
// C[8192][NC] = A[8192][KD] @ Bw^T; A (8192,KD) bf16, Bw (NC,KD) bf16 (n,k).
template<int KD, int NC, int TM, int TN>
__global__ __launch_bounds__(256) void k_gemmb(const unsigned short* __restrict__ A,
                                               const unsigned short* __restrict__ Bw,
                                               const float* __restrict__ bias,
                                               const float* __restrict__ resid,
                                               float* __restrict__ Cout,
                                               int scale_cols, float qs,
                                               const float* __restrict__ gamma,
                                               const float* __restrict__ beta,
                                               unsigned short* __restrict__ obf) {
    const int t = threadIdx.x;
    const int rb = blockIdx.x * TM, cb = blockIdx.y * TN;
    __shared__ __align__(16) unsigned short As[TM * 40];
    __shared__ __align__(16) unsigned short Bs[TN * 40];
    const int w = t >> 6, lane = t & 63;
    constexpr int QR = TM / 2, QC = TN / 2;
    constexpr int MR = QR / 16, NR = QC / 16;
    const int wr = (w & 1) * QR, wc = (w >> 1) * QC;
    const int fr = lane & 15, fq = (lane >> 4) * 8;
    f32x4 acc[MR][NR] = {};
    for (int k0 = 0; k0 < KD; k0 += 32) {
        __syncthreads();
        #pragma unroll
        for (int u = t; u < TM * 4; u += 256) {
            const int m = u >> 2, c = (u & 3) * 8;
            if constexpr (KD % 32 == 0) {
                *reinterpret_cast<short8*>(&As[m * 40 + c]) =
                    *reinterpret_cast<const short8*>(&A[(size_t)(rb + m) * KD + k0 + c]);
            } else {
                #pragma unroll
                for (int j = 0; j < 8; j++) {
                    const int kk = k0 + c + j;
                    As[m * 40 + c + j] = (kk < KD) ? A[(size_t)(rb + m) * KD + kk] : (unsigned short)0;
                }
            }
        }
        #pragma unroll
        for (int u = t; u < TN * 4; u += 256) {
            const int n = u >> 2, c = (u & 3) * 8;
            const int gn = cb + n;
            if (gn < NC) {
                if constexpr (KD % 32 == 0) {
                    *reinterpret_cast<short8*>(&Bs[n * 40 + c]) =
                        *reinterpret_cast<const short8*>(&Bw[(size_t)gn * KD + k0 + c]);
                } else {
                    #pragma unroll
                    for (int j = 0; j < 8; j++) {
                        const int kk = k0 + c + j;
                        Bs[n * 40 + c + j] = (kk < KD) ? Bw[(size_t)gn * KD + kk] : (unsigned short)0;
                    }
                }
            } else {
                short8 z = {};
                *reinterpret_cast<short8*>(&Bs[n * 40 + c]) = z;
            }
        }
        __syncthreads();
        short8 af[MR], bfr[NR];
        #pragma unroll
        for (int mi = 0; mi < MR; mi++)
            af[mi] = *reinterpret_cast<const short8*>(&As[(wr + mi * 16 + fr) * 40 + fq]);
        #pragma unroll
        for (int ni = 0; ni < NR; ni++)
            bfr[ni] = *reinterpret_cast<const short8*>(&Bs[(wc + ni * 16 + fr) * 40 + fq]);
        #pragma unroll
        for (int mi = 0; mi < MR; mi++) {
            #pragma unroll
            for (int ni = 0; ni < NR; ni++)
                acc[mi][ni] = __builtin_amdgcn_mfma_f32_16x16x32_bf16(af[mi], bfr[ni], acc[mi][ni], 0, 0, 0);
        }
    }
    const int cr = (lane >> 4) * 4, cc = lane & 15;
    #pragma unroll
    for (int mi = 0; mi < MR; mi++) {
        #pragma unroll
        for (int ni = 0; ni < NR; ni++) {
            #pragma unroll
            for (int r = 0; r < 4; r++) {
                const int row = rb + wr + mi * 16 + cr + r;
                const int col = cb + wc + ni * 16 + cc;
                if (col < NC) {
                    float v = acc[mi][ni][r] + (bias ? bias[col] : 0.f);
                    if (col < scale_cols) v *= qs;
                    if (resid) v += resid[(size_t)row * NC + col];
                    if (gamma) {
                        v = v * (gamma[col] * BN_SCALE) + beta[col];
                        v = v >= 0.f ? v : 0.2f * v;
                    }
                    Cout[(size_t)row * NC + col] = v;
                    if (obf) obf[(size_t)row * NC + col] = F2BF(v);
                }
            }
        }
    }
}

// ---------------------------------------------------------------- EdgeConv epilogue (fp32 out + bf16 copy)
template<int CO>
__global__ __launch_bounds__(256) void k_edgemax(const float* __restrict__ yz,
                                                 const int* __restrict__ idx,
                                                 const float* __restrict__ g,
                                                 const float* __restrict__ bb,
                                                 float* __restrict__ out,
                                                 unsigned short* __restrict__ outb) {
    constexpr int TPP = CO / 4;
    constexpr int PPB = 256 / TPP;
    const int t = threadIdx.x;
    const int p = t / TPP;
    const int cw = (t % TPP) * 4;
    const int i0 = blockIdx.x * PPB;
    const int bbase = (i0 >> 10) << 10;
    __shared__ int sidx[PPB][K_];
    for (int u = t; u < PPB * K_; u += 256) {
        int pp = u / K_, kk = u - pp * K_;
        sidx[pp][kk] = idx[(size_t)(i0 + pp) * K_ + kk];
    }
    __syncthreads();
    const int ig = i0 + p;
    float4 m = {-3e38f, -3e38f, -3e38f, -3e38f};
    #pragma unroll 4
    for (int k = 0; k < K_; k++) {
        const int jg = bbase + sidx[p][k];
        const float4 yv = *reinterpret_cast<const float4*>(&yz[(size_t)jg * 2 * CO + cw]);
        m.x = fmaxf(m.x, yv.x); m.y = fmaxf(m.y, yv.y);
        m.z = fmaxf(m.z, yv.z); m.w = fmaxf(m.w, yv.w);
    }
    const float4 yi = *reinterpret_cast<const float4*>(&yz[(size_t)ig * 2 * CO + cw]);
    const float4 zi = *reinterpret_cast<const float4*>(&yz[(size_t)ig * 2 * CO + CO + cw]);
    const float4 gv = *reinterpret_cast<const float4*>(&g[cw]);
    const float4 bv = *reinterpret_cast<const float4*>(&bb[cw]);
    float vals[4] = {m.x - yi.x + zi.x, m.y - yi.y + zi.y,
                     m.z - yi.z + zi.z, m.w - yi.w + zi.w};
    float gs[4] = {gv.x, gv.y, gv.z, gv.w};
    float bs[4] = {bv.x, bv.y, bv.z, bv.w};
    float4 o;
    float* op = &o.x;
    #pragma unroll
    for (int j = 0; j < 4; j++) {
        float h = vals[j] * (gs[j] * BN_SCALE) + bs[j];
        op[j] = h >= 0.f ? h : 0.2f * h;
    }
    *reinterpret_cast<float4*>(&out[(size_t)ig * CO + cw]) = o;
    #pragma unroll
    for (int j = 0; j < 4; j++) outb[(size_t)ig * CO + cw + j] = F2BF(op[j]);
}

// ---------------------------------------------------------------- attention (fp32 math, bf16 out)
template<int E>
__global__ __launch_bounds__(256) void k_attn(const float* __restrict__ qkv,
                                              unsigned short* __restrict__ o) {
    constexpr int H = 4, D = E / H, L = 8;
    const int n = blockIdx.x;
    const int t = threadIdx.x;
    const int h = t >> 6, lane = t & 63;
    __shared__ float sq[L][3 * E];
    __shared__ float so[L][E];
    for (int u = t; u < L * 3 * E; u += 256) {
        int l = u / (3 * E), r = u - l * (3 * E);
        sq[l][r] = qkv[(size_t)(l * N_ + n) * (3 * E) + r];
    }
    __syncthreads();
    const int l = lane >> 3, m = lane & 7;
    float s = 0.f;
    #pragma unroll 8
    for (int dd = 0; dd < D; dd++)
        s += sq[l][h * D + dd] * sq[m][E + h * D + dd];
    float mx = s;
    #pragma unroll
    for (int st = 1; st < 8; st <<= 1) mx = fmaxf(mx, __shfl_xor(mx, st, 64));
    float e = expf(s - mx);
    float sum = e;
    #pragma unroll
    for (int st = 1; st < 8; st <<= 1) sum += __shfl_xor(sum, st, 64);
    const float p = e / sum;
    float pm[8];
    #pragma unroll
    for (int mm = 0; mm < 8; mm++) pm[mm] = __shfl(p, (lane & 56) | mm, 64);
    #pragma unroll
    for (int j = 0; j < D / 8; j++) {
        const int dd = m + 8 * j;
        float a = 0.f;
        #pragma unroll
        for (int mm = 0; mm < 8; mm++) a += pm[mm] * sq[mm][2 * E + h * D + dd];
        so[l][h * D + dd] = a;
    }
    __syncthreads();
    for (int u = t; u < L * E; u += 256) {
        int l2 = u / E, e2 = u - l2 * E;
        o[(size_t)(l2 * N_ + n) * E + e2] = F2BF(so[l2][e2]);
    }
}

// ---------------------------------------------------------------- cat (bf16 -> bf16)
__global__ __launch_bounds__(256) void k_cat(const unsigned short* __restrict__ x1, const unsigned short* __restrict__ x2,
                                             const unsigned short* __restrict__ x3, const unsigned short* __restrict__ x4,
                                             unsigned short* __restrict__ cat) {
    int u = blockIdx.x * 256 + threadIdx.x;
    int p = u >> 9, c = u & 511;
    unsigned short v;
    if (c < 64)       v = x1[(size_t)p * 64 + c];
    else if (c < 128) v = x2[(size_t)p * 64 + (c - 64)];
    else if (c < 256) v = x3[(size_t)p * 128 + (c - 128)];
    else              v = x4[(size_t)p * 256 + (c - 256)];
    cat[u] = v;
}

// ---------------------------------------------------------------- pool (two-phase)
__global__ __launch_bounds__(256) void k_pool1(const float* __restrict__ h5,
                                               float* __restrict__ pmax,
                                               float* __restrict__ psum) {
    int c = blockIdx.x * 256 + threadIdx.x;
    int b = blockIdx.y, ch = blockIdx.z;
    float mx = -3e38f, sm = 0.f;
    for (int n = ch * 128; n < ch * 128 + 128; n++) {
        float v = h5[((size_t)b * N_ + n) * 1024 + c];
        mx = fmaxf(mx, v); sm += v;
    }
    pmax[((size_t)b * 8 + ch) * 1024 + c] = mx;
    psum[((size_t)b * 8 + ch) * 1024 + c] = sm;
}

__global__ __launch_bounds__(256) void k_pool2(const float* __restrict__ pmax,
                                               const float* __restrict__ psum,
                                               float* __restrict__ feat) {
    int c = blockIdx.x * 256 + threadIdx.x;
    int b = blockIdx.y;
    float mx = -3e38f, sm = 0.f;
    #pragma unroll
    for (int ch = 0; ch < 8; ch++) {
        mx = fmaxf(mx, pmax[((size_t)b * 8 + ch) * 1024 + c]);
        sm += psum[((size_t)b * 8 + ch) * 1024 + c];
    }
    feat[b * 2048 + c] = mx;
    feat[b * 2048 + 1024 + c] = sm * (1.f / 1024.f);
}

// ---------------------------------------------------------------- FC head
__global__ __launch_bounds__(256) void k_fc1(const float* __restrict__ feat, const float* __restrict__ l1wT,
                                             const float* __restrict__ g6, const float* __restrict__ b6,
                                             float* __restrict__ f1) {
    int oc = blockIdx.x, b = blockIdx.y, t = threadIdx.x;
    __shared__ float fin[2048];
    __shared__ float psum[4][64];
    for (int u = t; u < 2048; u += 256) fin[u] = feat[b * 2048 + u];
    __syncthreads();
    int ol = t & 63, kc = t >> 6;
    int o = oc * 64 + ol;
    float acc = 0.f;
    for (int c = kc * 512; c < kc * 512 + 512; c++) acc += fin[c] * l1wT[(size_t)c * 512 + o];
    psum[kc][ol] = acc;
    __syncthreads();
    if (t < 64) {
        int oo = oc * 64 + t;
        float a = psum[0][t] + psum[1][t] + psum[2][t] + psum[3][t];
        float h = a * (g6[oo] * BN_SCALE) + b6[oo];
        f1[b * 512 + oo] = h >= 0.f ? h : 0.2f * h;
    }
}

__global__ __launch_bounds__(256) void k_fc2(const float* __restrict__ f1, const float* __restrict__ l2wT,
                                             const float* __restrict__ l2b,
                                             const float* __restrict__ g7, const float* __restrict__ b7,
                                             float* __restrict__ f2) {
    int b = blockIdx.x, t = threadIdx.x;
    __shared__ float fin[512];
    for (int u = t; u < 512; u += 256) fin[u] = f1[b * 512 + u];
    __syncthreads();
    if (t < 256) {
        int o = t;
        float acc = 0.f;
        for (int c = 0; c < 512; c++) acc += fin[c] * l2wT[(size_t)c * 256 + o];
        acc += l2b[o];
        float h = acc * (g7[o] * BN_SCALE) + b7[o];
        f2[b * 256 + o] = h >= 0.f ? h : 0.2f * h;
    }
}

__global__ __launch_bounds__(64) void k_fc3(const float* __restrict__ f2, const float* __restrict__ l3wT,
                                            const float* __restrict__ l3b,
                                            void* __restrict__ out, const int* __restrict__ flag) {
    int b = blockIdx.x, t = threadIdx.x;
    __shared__ float fin[256];
    for (int u = t; u < 256; u += 64) fin[u] = f2[b * 256 + u];
    __syncthreads();
    if (t < 40) {
        float acc = 0.f;
        for (int c = 0; c < 256; c++) acc += fin[c] * l3wT[(size_t)c * 40 + t];
        acc += l3b[t];
        if (*flag) ((__hip_bfloat16*)out)[b * 40 + t] = __float2bfloat16(acc);
        else       ((float*)out)[b * 40 + t] = acc;
    }
}

// ================================================================ host
extern "C" void kernel_launch(void* const* d_in, const int* in_sizes, int n_in,
                              void* d_out, int out_size, void* d_ws, size_t ws_size,
                              hipStream_t stream) {
    auto us = [&](int i) { return (const unsigned short*)d_in[i]; };

    float* ws = (float*)d_ws;
    size_t off = 0;
    auto A = [&](size_t n) { float* p = ws + off; off += (n + 3) & ~(size_t)3; return p; };
    auto AU = [&](size_t n) { return (unsigned short*)A((n + 1) / 2); };
    float* xf0  = A((size_t)BN_ * 3);
    float* x1   = A((size_t)BN_ * 64);
    float* x2   = A((size_t)BN_ * 64);
    float* x3   = A((size_t)BN_ * 128);
    float* x4   = A((size_t)BN_ * 256);
    float* h5   = A((size_t)BN_ * 1024);   // also pd scratch
    float* feat = A(8 * 2048);
    float* f1   = A(8 * 512);
    float* f2   = A(8 * 256);
    float* xx   = A(BN_);
    int*   idx  = (int*)A((size_t)BN_ * K_);
    int*   flag = (int*)A(4);
    float* qkvw = A((size_t)BN_ * 768);   // qkv / yz / knn-split scratch
    // bf16 activation copies
    unsigned short* xf0b = AU((size_t)BN_ * 3);
    unsigned short* x1b  = AU((size_t)BN_ * 64);
    unsigned short* x2b  = AU((size_t)BN_ * 64);
    unsigned short* x3b  = AU((size_t)BN_ * 128);
    unsigned short* x4b  = AU((size_t)BN_ * 256);
    unsigned short* owb  = AU((size_t)BN_ * 256);
    unsigned short* catb = AU((size_t)BN_ * 512);
    float* pmax = A(8 * 8 * 1024);
    float* psum = A(8 * 8 * 1024);
    // bf16 weights (n,k) layouts
    unsigned short* w1yzb = AU(128 * 3);
    unsigned short* w2yzb = AU(128 * 64);
    unsigned short* w3yzb = AU(256 * 64);
    unsigned short* w4yzb = AU(512 * 128);
    unsigned short* a1wib = AU(192 * 64);  unsigned short* a1wob = AU(64 * 64);
    unsigned short* a2wib = AU(192 * 64);  unsigned short* a2wob = AU(64 * 64);
    unsigned short* a3wib = AU(384 * 128); unsigned short* a3wob = AU(128 * 128);
    unsigned short* a4wib = AU(768 * 256); unsigned short* a4wob = AU(256 * 256);
    unsigned short* w5b   = AU(1024 * 512);
    // fp32 fc weights (transposed)
    float* l1wT  = A(2048 * 512);
    float* l2wT  = A(512 * 256);
    float* l3wT  = A(256 * 40);
    // converted vectors (fp32)
    float* g1f = A(64);   float* b1f = A(64);
    float* g2f = A(64);   float* b2f = A(64);
    float* g3f = A(128);  float* b3f = A(128);
    float* g4f = A(256);  float* b4f = A(256);
    float* bi1 = A(192);  float* bo1 = A(64);
    float* bi2 = A(192);  float* bo2 = A(64);
    float* bi3 = A(384);  float* bo3 = A(128);
    float* bi4 = A(768);  float* bo4 = A(256);
    float* g5f = A(1024); float* b5f = A(1024);
    float* g6f = A(512);  float* b6f = A(512);
    float* l2bf = A(256);
    float* g7f = A(256);  float* b7f = A(256);
    float* l3bf = A(40);

    // knn split buffers alias qkvw (dead during the kNN phase of each layer)
    unsigned short* xa = (unsigned short*)qkvw;                 // <= 8192*512 bf16 = 8 MB
    unsigned short* xb = (unsigned short*)qkvw + (size_t)BN_ * 512;

    k_detect<<<1, 1, 0, stream>>>(us(2), us(5), us(8), us(11), us(30), us(33), us(37), flag);

    TList tl; int nb = 0; int k = 0;
    auto add = [&](int i, void* dst, int O, int I, int mode) {
        tl.p[k].src = d_in[i]; tl.p[k].dst = dst; tl.p[k].O = O; tl.p[k].I = I;
        tl.p[k].blk0 = nb; tl.p[k].mode = mode;
        nb += (O * I + 255) / 256; k++;
    };
    add(0,  xf0,   BN_ * 3, 1, 0);
    add(0,  xf0b,  BN_ * 3, 1, 2);
    add(1,  w1yzb, 64, 6, 3);
    add(4,  w2yzb, 64, 128, 3);
    add(7,  w3yzb, 128, 128, 3);
    add(10, w4yzb, 256, 256, 3);
    add(13, a1wib, 192, 64, 2);
    add(15, a1wob, 64, 64, 2);
    add(17, a2wib, 192, 64, 2);
    add(19, a2wob, 64, 64, 2);
    add(21, a3wib, 384, 128, 2);
    add(23, a3wob, 128, 128, 2);
    add(25, a4wib, 768, 256, 2);
    add(27, a4wob, 256, 256, 2);
    add(29, w5b,   1024, 512, 2);
    add(32, l1wT,  512, 2048, 0);
    add(35, l2wT,  256, 512, 0);
    add(39, l3wT,  40, 256, 0);
    add(2,  g1f, 64, 1, 0);   add(3,  b1f, 64, 1, 0);
    add(5,  g2f, 64, 1, 0);   add(6,  b2f, 64, 1, 0);
    add(8,  g3f, 128, 1, 0);  add(9,  b3f, 128, 1, 0);
    add(11, g4f, 256, 1, 0);  add(12, b4f, 256, 1, 0);
    add(14, bi1, 192, 1, 0);  add(16, bo1, 64, 1, 0);
    add(18, bi2, 192, 1, 0);  add(20, bo2, 64, 1, 0);
    add(22, bi3, 384, 1, 0);  add(24, bo3, 128, 1, 0);
    add(26, bi4, 768, 1, 0);  add(28, bo4, 256, 1, 0);
    add(30, g5f, 1024, 1, 0); add(31, b5f, 1024, 1, 0);
    add(33, g6f, 512, 1, 0);  add(34, b6f, 512, 1, 0);
    add(36, l2bf, 256, 1, 0);
    add(37, g7f, 256, 1, 0);  add(38, b7f, 256, 1, 0);
    add(40, l3bf, 40, 1, 0);
    k_prep<<<nb, 256, 0, stream>>>(tl, k, flag);

    float* yzb = qkvw;                 // fp32 yz scratch (after kNN phase)
    float* pd  = h5;                   // pd scratch (h5 dead until conv5)
    const dim3 pdmg(8, 8, 8);          // 128x128 tiles per batch

    // layer 1  (C=3 -> 64)
    k_norms<<<BN_ / 256, 256, 0, stream>>>(xf0, xx, 3);
    k_split<3, 32><<<(BN_ * 32) / 256, 256, 0, stream>>>(xf0, xa, xb);
    k_pdm<32><<<pdmg, 256, 0, stream>>>(xa, xb, xx, pd);
    k_sel<<<BN_ / 4, 256, 0, stream>>>(pd, idx);
    k_gemmb<3, 128, 64, 64><<<dim3(128, 2), 256, 0, stream>>>(xf0b, w1yzb, nullptr, nullptr, yzb, 0, 1.f, nullptr, nullptr, nullptr);
    k_edgemax<64><<<BN_ / 16, 256, 0, stream>>>(yzb, idx, g1f, b1f, x1, x1b);
    k_gemmb<64, 192, 64, 64><<<dim3(128, 3), 256, 0, stream>>>(x1b, a1wib, bi1, nullptr, qkvw, 64, 0.25f, nullptr, nullptr, nullptr);
    k_attn<64><<<N_, 256, 0, stream>>>(qkvw, owb);
    k_gemmb<64, 64, 64, 64><<<dim3(128, 1), 256, 0, stream>>>(owb, a1wob, bo1, x1, x1, 0, 1.f, nullptr, nullptr, x1b);

    // layer 2  (C=64 -> 64)
    k_norms<<<BN_ / 256, 256, 0, stream>>>(x1, xx, 64);
    k_split<64, 256><<<(BN_ * 256) / 256, 256, 0, stream>>>(x1, xa, xb);
    k_pdm<256><<<pdmg, 256, 0, stream>>>(xa, xb, xx, pd);
    k_sel<<<BN_ / 4, 256, 0, stream>>>(pd, idx);
    k_gemmb<64, 128, 64, 64><<<dim3(128, 2), 256, 0, stream>>>(x1b, w2yzb, nullptr, nullptr, yzb, 0, 1.f, nullptr, nullptr, nullptr);
    k_edgemax<64><<<BN_ / 16, 256, 0, stream>>>(yzb, idx, g2f, b2f, x2, x2b);
    k_gemmb<64, 192, 64, 64><<<dim3(128, 3), 256, 0, stream>>>(x2b, a2wib, bi2, nullptr, qkvw, 64, 0.25f, nullptr, nullptr, nullptr);
    k_attn<64><<<N_, 256, 0, stream>>>(qkvw, owb);
    k_gemmb<64, 64, 64, 64><<<dim3(128, 1), 256, 0, stream>>>(owb, a2wob, bo2, x2, x2, 0, 1.f, nullptr, nullptr, x2b);

    // layer 3  (C=64 -> 128)
    k_norms<<<BN_ / 256, 256, 0, stream>>>(x2, xx, 64);
    k_split<64, 256><<<(BN_ * 256) / 256, 256, 0, stream>>>(x2, xa, xb);
    k_pdm<256><<<pdmg, 256, 0, stream>>>(xa, xb, xx, pd);
    k_sel<<<BN_ / 4, 256, 0, stream>>>(pd, idx);
    k_gemmb<64, 256, 64, 64><<<dim3(128, 4), 256, 0, stream>>>(x2b, w3yzb, nullptr, nullptr, yzb, 0, 1.f, nullptr, nullptr, nullptr);
    k_edgemax<128><<<BN_ / 8, 256, 0, stream>>>(yzb, idx, g3f, b3f, x3, x3b);
    k_gemmb<128, 384, 64, 128><<<dim3(128, 3), 256, 0, stream>>>(x3b, a3wib, bi3, nullptr, qkvw, 128, 0.17677669529663687f, nullptr, nullptr, nullptr);
    k_attn<128><<<N_, 256, 0, stream>>>(qkvw, owb);
    k_gemmb<128, 128, 64, 64><<<dim3(128, 2), 256, 0, stream>>>(owb, a3wob, bo3, x3, x3, 0, 1.f, nullptr, nullptr, x3b);

    // layer 4  (C=128 -> 256)
    k_norms<<<BN_ / 256, 256, 0, stream>>>(x3, xx, 128);
    k_split<128, 512><<<(BN_ * 512) / 256, 256, 0, stream>>>(x3, xa, xb);
    k_pdm<512><<<pdmg, 256, 0, stream>>>(xa, xb, xx, pd);
    k_sel<<<BN_ / 4, 256, 0, stream>>>(pd, idx);
    k_gemmb<128, 512, 128, 128><<<dim3(64, 4), 256, 0, stream>>>(x3b, w4yzb, nullptr, nullptr, yzb, 0, 1.f, nullptr, nullptr, nullptr);
    k_edgemax<256><<<BN_ / 4, 256, 0, stream>>>(yzb, idx, g4f, b4f, x4, x4b);
    k_gemmb<256, 768, 128, 128><<<dim3(64, 6), 256, 0, stream>>>(x4b, a4wib, bi4, nullptr, qkvw, 256, 0.125f, nullptr, nullptr, nullptr);
    k_attn<256><<<N_, 256, 0, stream>>>(qkvw, owb);
    k_gemmb<256, 256, 64, 128><<<dim3(128, 2), 256, 0, stream>>>(owb, a4wob, bo4, x4, x4, 0, 1.f, nullptr, nullptr, x4b);

    // head
    k_cat<<<(BN_ * 512) / 256, 256, 0, stream>>>(x1b, x2b, x3b, x4b, catb);
    k_gemmb<512, 1024, 128, 128><<<dim3(64, 8), 256, 0, stream>>>(catb, w5b, nullptr, nullptr, h5, 0, 1.f, g5f, b5f, nullptr);
    k_pool1<<<dim3(4, 8, 8), 256, 0, stream>>>(h5, pmax, psum);
    k_pool2<<<dim3(4, 8), 256, 0, stream>>>(pmax, psum, feat);
    k_fc1<<<dim3(8, 8), 256, 0, stream>>>(feat, l1wT, g6f, b6f, f1);
    k_fc2<<<8, 256, 0, stream>>>(f1, l2wT, l2bf, g7f, b7f, f2);
    k_fc3<<<8, 64, 0, stream>>>(f2, l3wT, l3bf, d_out, flag);
}

// Round 18
// 691.245 us; speedup vs baseline: 1.2163x; 1.1201x over previous
//
#include <hip/hip_runtime.h>
#include <hip/hip_bf16.h>

#define B_ 8
#define N_ 1024
#define K_ 20
#define BN_ (B_*N_)

#define BN_SCALE 0.9999950000374997f

typedef __attribute__((ext_vector_type(8))) short short8;
typedef __attribute__((ext_vector_type(4))) float f32x4;

__device__ __forceinline__ float US2F(unsigned short u) {
    union { unsigned u; float f; } c; c.u = ((unsigned)u) << 16; return c.f;
}
__device__ __forceinline__ unsigned short F2BF(float f) {   // RNE fp32->bf16
    union { float f; unsigned u; } c; c.f = f;
    unsigned r = c.u + 0x7FFF + ((c.u >> 16) & 1);
    return (unsigned short)(r >> 16);
}

// ---------------------------------------------------------------- dtype detect
__global__ void k_detect(const unsigned short* g1, const unsigned short* g2,
                         const unsigned short* g3, const unsigned short* g4,
                         const unsigned short* g5, const unsigned short* g6,
                         const unsigned short* g7, int* flag) {
    const unsigned short* gs[7] = {g1, g2, g3, g4, g5, g6, g7};
    int cnt = 0;
    for (int i = 0; i < 7; i++) {
        float v = US2F(gs[i][0]);
        if (v > 0.5f && v < 1.5f) cnt++;
    }
    *flag = (cnt >= 4) ? 1 : 0;   // 1 = bf16 inputs, 0 = fp32 inputs
}

// ---------------------------------------------------------------- prep
// mode 0: fp32 transpose (O,I)->(I,O).  mode 2: bf16 copy (keeps (n,k)).
// mode 3: edge pair -> bf16 (2O, C): rows [0,O)=wn, [O,2O)=wc.
struct TPar { const void* src; void* dst; int O, I, blk0, mode; };
struct TList { TPar p[44]; };

__global__ __launch_bounds__(256) void k_prep(TList tl, int nent, const int* flag) {
    const int isbf = *flag;
    int blk = blockIdx.x;
    int wi = 0;
    for (int j = nent - 1; j >= 0; j--) { if (blk >= tl.p[j].blk0) { wi = j; break; } }
    const TPar p = tl.p[wi];
    int e = (blk - p.blk0) * 256 + threadIdx.x;
    int n = p.O * p.I;
    if (e >= n) return;
    int o = e / p.I, i = e - o * p.I;
    float v = isbf ? US2F(((const unsigned short*)p.src)[e])
                   : ((const float*)p.src)[e];
    if (p.mode == 0) {
        ((float*)p.dst)[(size_t)i * p.O + o] = v;
    } else if (p.mode == 2) {
        ((unsigned short*)p.dst)[e] = F2BF(v);
    } else {
        const int C = p.I >> 1;
        if (i < C) ((unsigned short*)p.dst)[(size_t)o * C + i] = F2BF(v);
        else       ((unsigned short*)p.dst)[(size_t)(p.O + o) * C + (i - C)] = F2BF(v);
    }
}

// ---------------------------------------------------------------- norms
__global__ __launch_bounds__(256) void k_norms(const float* __restrict__ xf,
                                               float* __restrict__ xx, int C) {
    int i = blockIdx.x * 256 + threadIdx.x;
    if (i >= BN_) return;
    const float* p = xf + (size_t)i * C;
    float s = 0.f;
    for (int c = 0; c < C; c++) s += p[c] * p[c];
    xx[i] = s;
}

// ---------------------------------------------------------------- kNN split:
// x (fp32) -> augmented bf16 rows (exact-split): xa=[hi,lo,hi,lo],
// xb=[hi,hi,lo,lo], zero-padded to KP.  dot(xa_i, xb_j) over KP =
// (hi+lo)_i . (hi+lo)_j with fp32 MFMA accumulation (error ~2^-17).
template<int C, int KP>
__global__ __launch_bounds__(256) void k_split(const float* __restrict__ x,
                                               unsigned short* __restrict__ xa,
                                               unsigned short* __restrict__ xb) {
    const int e = blockIdx.x * 256 + threadIdx.x;
    if (e >= BN_ * KP) return;
    const int i = e / KP, p = e - i * KP;
    unsigned short va = 0, vb = 0;
    if (p < 4 * C) {
        const int seg = p / C, c = p - seg * C;
        const float v = x[(size_t)i * C + c];
        const unsigned short h = F2BF(v);
        const unsigned short l = F2BF(v - US2F(h));
        va = (seg & 1) ? l : h;           // hi,lo,hi,lo
        vb = (seg < 2) ? h : l;           // hi,hi,lo,lo
    }
    xa[e] = va;
    xb[e] = vb;
}

// ---------------------------------------------------------------- kNN phase 1 (MFMA):
// pd[b][i][j] = 2*dot(xa_i, xb_j) - xx_j.  128x128 tile, 4 waves x 64x64
// quadrant, 4x4 mfma_f32_16x16x32_bf16.
template<int KP>
__global__ __launch_bounds__(256) void k_pdm(const unsigned short* __restrict__ xa,
                                             const unsigned short* __restrict__ xb,
                                             const float* __restrict__ xx,
                                             float* __restrict__ pd) {
    const int b = blockIdx.z;
    const int rb = blockIdx.x * 128, cb = blockIdx.y * 128;
    const unsigned short* Ab = xa + (size_t)b * N_ * KP;
    const unsigned short* Bb = xb + (size_t)b * N_ * KP;
    const float* xxb = xx + (size_t)b * N_;
    const int t = threadIdx.x;
    __shared__ __align__(16) unsigned short As[128 * 40];
    __shared__ __align__(16) unsigned short Bs[128 * 40];
    const int w = t >> 6, lane = t & 63;
    const int wr = (w & 1) * 64, wc = (w >> 1) * 64;
    const int fr = lane & 15, fq = (lane >> 4) * 8;
    f32x4 acc[4][4] = {};
    for (int k0 = 0; k0 < KP; k0 += 32) {
        __syncthreads();
        #pragma unroll
        for (int u = t; u < 512; u += 256) {
            const int m = u >> 2, c = (u & 3) * 8;
            *reinterpret_cast<short8*>(&As[m * 40 + c]) =
                *reinterpret_cast<const short8*>(&Ab[(size_t)(rb + m) * KP + k0 + c]);
        }
        #pragma unroll
        for (int u = t; u < 512; u += 256) {
            const int n = u >> 2, c = (u & 3) * 8;
            *reinterpret_cast<short8*>(&Bs[n * 40 + c]) =
                *reinterpret_cast<const short8*>(&Bb[(size_t)(cb + n) * KP + k0 + c]);
        }
        __syncthreads();
        short8 af[4], bfr[4];
        #pragma unroll
        for (int mi = 0; mi < 4; mi++)
            af[mi] = *reinterpret_cast<const short8*>(&As[(wr + mi * 16 + fr) * 40 + fq]);
        #pragma unroll
        for (int ni = 0; ni < 4; ni++)
            bfr[ni] = *reinterpret_cast<const short8*>(&Bs[(wc + ni * 16 + fr) * 40 + fq]);
        #pragma unroll
        for (int mi = 0; mi < 4; mi++) {
            #pragma unroll
            for (int ni = 0; ni < 4; ni++)
                acc[mi][ni] = __builtin_amdgcn_mfma_f32_16x16x32_bf16(af[mi], bfr[ni], acc[mi][ni], 0, 0, 0);
        }
    }
    float* pdb = pd + (size_t)b * N_ * N_;
    const int cr = (lane >> 4) * 4, cc = lane & 15;
    #pragma unroll
    for (int mi = 0; mi < 4; mi++) {
        #pragma unroll
        for (int ni = 0; ni < 4; ni++) {
            #pragma unroll
            for (int r = 0; r < 4; r++) {
                const int row = rb + wr + mi * 16 + cr + r;
                const int col = cb + wc + ni * 16 + cc;
                pdb[(size_t)row * N_ + col] = 2.f * acc[mi][ni][r] - xxb[col];
            }
        }
    }
}

// ---------------------------------------------------------------- kNN phase 2
// 32-bit key top-20: key = (ordered_bits & ~1023) | (1023 - j). Single-op
// v_max_u32 rounds (the R17 u64 keys cost 3 ops per compare -> 45us/dispatch).
// Value compare precision 2^-14 rel; near-equidistant swaps only.
__global__ __launch_bounds__(256) void k_sel(const float* __restrict__ pd,
                                             int* __restrict__ idx) {
    const int w = threadIdx.x >> 6, lane = threadIdx.x & 63;
    const int i = blockIdx.x * 4 + w;          // 0..8191
    const int b = i >> 10;
    const float* row = pd + (size_t)b * N_ * N_ + (size_t)(i & 1023) * N_;
    unsigned key[16];
    #pragma unroll
    for (int q = 0; q < 16; q++) {
        const int j = q * 64 + lane;
        unsigned bits = __float_as_uint(row[j]);
        bits = (bits & 0x80000000u) ? ~bits : (bits | 0x80000000u);
        key[q] = (bits & 0xFFFFFC00u) | (unsigned)(N_ - 1 - j);
    }
    int myj = 0;
    for (int kk = 0; kk < K_; kk++) {
        unsigned m = key[0];
        #pragma unroll
        for (int u = 1; u < 16; u++) m = key[u] > m ? key[u] : m;
        #pragma unroll
        for (int s = 1; s < 64; s <<= 1) {
            unsigned o = (unsigned)__shfl_xor((int)m, s, 64);
            m = o > m ? o : m;
        }
        const int j = N_ - 1 - (int)(m & 1023u);
        if (lane == kk) myj = j;
        #pragma unroll
        for (int u = 0; u < 16; u++)
            if (key[u] == m) key[u] = 0u;      // below any plausible real key
    }
    if (lane < K_) idx[(size_t)i * K_ + lane] = myj;
}

// ---------------------------------------------------------------- MFMA bf16 GEMM
// C[8192][NC] = A[8192][KD] @ Bw^T; A (8192,KD) bf16, Bw (NC,KD) bf16 (n,k).
template<int KD, int NC, int TM, int TN>
__global__ __launch_bounds__(256) void k_gemmb(const unsigned short* __restrict__ A,
                                               const unsigned short* __restrict__ Bw,
                                               const float* __restrict__ bias,
                                               const float* __restrict__ resid,
                                               float* __restrict__ Cout,
                                               int scale_cols, float qs,
                                               const float* __restrict__ gamma,
                                               const float* __restrict__ beta,
                                               unsigned short* __restrict__ obf) {
    const int t = threadIdx.x;
    const int rb = blockIdx.x * TM, cb = blockIdx.y * TN;
    __shared__ __align__(16) unsigned short As[TM * 40];
    __shared__ __align__(16) unsigned short Bs[TN * 40];
    const int w = t >> 6, lane = t & 63;
    constexpr int QR = TM / 2, QC = TN / 2;
    constexpr int MR = QR / 16, NR = QC / 16;
    const int wr = (w & 1) * QR, wc = (w >> 1) * QC;
    const int fr = lane & 15, fq = (lane >> 4) * 8;
    f32x4 acc[MR][NR] = {};
    for (int k0 = 0; k0 < KD; k0 += 32) {
        __syncthreads();
        #pragma unroll
        for (int u = t; u < TM * 4; u += 256) {
            const int m = u >> 2, c = (u & 3) * 8;
            if constexpr (KD % 32 == 0) {
                *reinterpret_cast<short8*>(&As[m * 40 + c]) =
                    *reinterpret_cast<const short8*>(&A[(size_t)(rb + m) * KD + k0 + c]);
            } else {
                #pragma unroll
                for (int j = 0; j < 8; j++) {
                    const int kk = k0 + c + j;
                    As[m * 40 + c + j] = (kk < KD) ? A[(size_t)(rb + m) * KD + kk] : (unsigned short)0;
                }
            }
        }
        #pragma unroll
        for (int u = t; u < TN * 4; u += 256) {
            const int n = u >> 2, c = (u & 3) * 8;
            const int gn = cb + n;
            if (gn < NC) {
                if constexpr (KD % 32 == 0) {
                    *reinterpret_cast<short8*>(&Bs[n * 40 + c]) =
                        *reinterpret_cast<const short8*>(&Bw[(size_t)gn * KD + k0 + c]);
                } else {
                    #pragma unroll
                    for (int j = 0; j < 8; j++) {
                        const int kk = k0 + c + j;
                        Bs[n * 40 + c + j] = (kk < KD) ? Bw[(size_t)gn * KD + kk] : (unsigned short)0;
                    }
                }
            } else {
                short8 z = {};
                *reinterpret_cast<short8*>(&Bs[n * 40 + c]) = z;
            }
        }
        __syncthreads();
        short8 af[MR], bfr[NR];
        #pragma unroll
        for (int mi = 0; mi < MR; mi++)
            af[mi] = *reinterpret_cast<const short8*>(&As[(wr + mi * 16 + fr) * 40 + fq]);
        #pragma unroll
        for (int ni = 0; ni < NR; ni++)
            bfr[ni] = *reinterpret_cast<const short8*>(&Bs[(wc + ni * 16 + fr) * 40 + fq]);
        #pragma unroll
        for (int mi = 0; mi < MR; mi++) {
            #pragma unroll
            for (int ni = 0; ni < NR; ni++)
                acc[mi][ni] = __builtin_amdgcn_mfma_f32_16x16x32_bf16(af[mi], bfr[ni], acc[mi][ni], 0, 0, 0);
        }
    }
    const int cr = (lane >> 4) * 4, cc = lane & 15;
    #pragma unroll
    for (int mi = 0; mi < MR; mi++) {
        #pragma unroll
        for (int ni = 0; ni < NR; ni++) {
            #pragma unroll
            for (int r = 0; r < 4; r++) {
                const int row = rb + wr + mi * 16 + cr + r;
                const int col = cb + wc + ni * 16 + cc;
                if (col < NC) {
                    float v = acc[mi][ni][r] + (bias ? bias[col] : 0.f);
                    if (col < scale_cols) v *= qs;
                    if (resid) v += resid[(size_t)row * NC + col];
                    if (gamma) {
                        v = v * (gamma[col] * BN_SCALE) + beta[col];
                        v = v >= 0.f ? v : 0.2f * v;
                    }
                    Cout[(size_t)row * NC + col] = v;
                    if (obf) obf[(size_t)row * NC + col] = F2BF(v);
                }
            }
        }
    }
}

// ---------------------------------------------------------------- EdgeConv epilogue (fp32 out + bf16 copy)
template<int CO>
__global__ __launch_bounds__(256) void k_edgemax(const float* __restrict__ yz,
                                                 const int* __restrict__ idx,
                                                 const float* __restrict__ g,
                                                 const float* __restrict__ bb,
                                                 float* __restrict__ out,
                                                 unsigned short* __restrict__ outb) {
    constexpr int TPP = CO / 4;
    constexpr int PPB = 256 / TPP;
    const int t = threadIdx.x;
    const int p = t / TPP;
    const int cw = (t % TPP) * 4;
    const int i0 = blockIdx.x * PPB;
    const int bbase = (i0 >> 10) << 10;
    __shared__ int sidx[PPB][K_];
    for (int u = t; u < PPB * K_; u += 256) {
        int pp = u / K_, kk = u - pp * K_;
        sidx[pp][kk] = idx[(size_t)(i0 + pp) * K_ + kk];
    }
    __syncthreads();
    const int ig = i0 + p;
    float4 m = {-3e38f, -3e38f, -3e38f, -3e38f};
    #pragma unroll 4
    for (int k = 0; k < K_; k++) {
        const int jg = bbase + sidx[p][k];
        const float4 yv = *reinterpret_cast<const float4*>(&yz[(size_t)jg * 2 * CO + cw]);
        m.x = fmaxf(m.x, yv.x); m.y = fmaxf(m.y, yv.y);
        m.z = fmaxf(m.z, yv.z); m.w = fmaxf(m.w, yv.w);
    }
    const float4 yi = *reinterpret_cast<const float4*>(&yz[(size_t)ig * 2 * CO + cw]);
    const float4 zi = *reinterpret_cast<const float4*>(&yz[(size_t)ig * 2 * CO + CO + cw]);
    const float4 gv = *reinterpret_cast<const float4*>(&g[cw]);
    const float4 bv = *reinterpret_cast<const float4*>(&bb[cw]);
    float vals[4] = {m.x - yi.x + zi.x, m.y - yi.y + zi.y,
                     m.z - yi.z + zi.z, m.w - yi.w + zi.w};
    float gs[4] = {gv.x, gv.y, gv.z, gv.w};
    float bs[4] = {bv.x, bv.y, bv.z, bv.w};
    float4 o;
    float* op = &o.x;
    #pragma unroll
    for (int j = 0; j < 4; j++) {
        float h = vals[j] * (gs[j] * BN_SCALE) + bs[j];
        op[j] = h >= 0.f ? h : 0.2f * h;
    }
    *reinterpret_cast<float4*>(&out[(size_t)ig * CO + cw]) = o;
    #pragma unroll
    for (int j = 0; j < 4; j++) outb[(size_t)ig * CO + cw + j] = F2BF(op[j]);
}

// ---------------------------------------------------------------- attention (fp32 math, bf16 out)
template<int E>
__global__ __launch_bounds__(256) void k_attn(const float* __restrict__ qkv,
                                              unsigned short* __restrict__ o) {
    constexpr int H = 4, D = E / H, L = 8;
    const int n = blockIdx.x;
    const int t = threadIdx.x;
    const int h = t >> 6, lane = t & 63;
    __shared__ float sq[L][3 * E];
    __shared__ float so[L][E];
    for (int u = t; u < L * 3 * E; u += 256) {
        int l = u / (3 * E), r = u - l * (3 * E);
        sq[l][r] = qkv[(size_t)(l * N_ + n) * (3 * E) + r];
    }
    __syncthreads();
    const int l = lane >> 3, m = lane & 7;
    float s = 0.f;
    #pragma unroll 8
    for (int dd = 0; dd < D; dd++)
        s += sq[l][h * D + dd] * sq[m][E + h * D + dd];
    float mx = s;
    #pragma unroll
    for (int st = 1; st < 8; st <<= 1) mx = fmaxf(mx, __shfl_xor(mx, st, 64));
    float e = expf(s - mx);
    float sum = e;
    #pragma unroll
    for (int st = 1; st < 8; st <<= 1) sum += __shfl_xor(sum, st, 64);
    const float p = e / sum;
    float pm[8];
    #pragma unroll
    for (int mm = 0; mm < 8; mm++) pm[mm] = __shfl(p, (lane & 56) | mm, 64);
    #pragma unroll
    for (int j = 0; j < D / 8; j++) {
        const int dd = m + 8 * j;
        float a = 0.f;
        #pragma unroll
        for (int mm = 0; mm < 8; mm++) a += pm[mm] * sq[mm][2 * E + h * D + dd];
        so[l][h * D + dd] = a;
    }
    __syncthreads();
    for (int u = t; u < L * E; u += 256) {
        int l2 = u / E, e2 = u - l2 * E;
        o[(size_t)(l2 * N_ + n) * E + e2] = F2BF(so[l2][e2]);
    }
}

// ---------------------------------------------------------------- cat (bf16 -> bf16)
__global__ __launch_bounds__(256) void k_cat(const unsigned short* __restrict__ x1, const unsigned short* __restrict__ x2,
                                             const unsigned short* __restrict__ x3, const unsigned short* __restrict__ x4,
                                             unsigned short* __restrict__ cat) {
    int u = blockIdx.x * 256 + threadIdx.x;
    int p = u >> 9, c = u & 511;
    unsigned short v;
    if (c < 64)       v = x1[(size_t)p * 64 + c];
    else if (c < 128) v = x2[(size_t)p * 64 + (c - 64)];
    else if (c < 256) v = x3[(size_t)p * 128 + (c - 128)];
    else              v = x4[(size_t)p * 256 + (c - 256)];
    cat[u] = v;
}

// ---------------------------------------------------------------- pool (two-phase)
__global__ __launch_bounds__(256) void k_pool1(const float* __restrict__ h5,
                                               float* __restrict__ pmax,
                                               float* __restrict__ psum) {
    int c = blockIdx.x * 256 + threadIdx.x;
    int b = blockIdx.y, ch = blockIdx.z;
    float mx = -3e38f, sm = 0.f;
    for (int n = ch * 128; n < ch * 128 + 128; n++) {
        float v = h5[((size_t)b * N_ + n) * 1024 + c];
        mx = fmaxf(mx, v); sm += v;
    }
    pmax[((size_t)b * 8 + ch) * 1024 + c] = mx;
    psum[((size_t)b * 8 + ch) * 1024 + c] = sm;
}

__global__ __launch_bounds__(256) void k_pool2(const float* __restrict__ pmax,
                                               const float* __restrict__ psum,
                                               float* __restrict__ feat) {
    int c = blockIdx.x * 256 + threadIdx.x;
    int b = blockIdx.y;
    float mx = -3e38f, sm = 0.f;
    #pragma unroll
    for (int ch = 0; ch < 8; ch++) {
        mx = fmaxf(mx, pmax[((size_t)b * 8 + ch) * 1024 + c]);
        sm += psum[((size_t)b * 8 + ch) * 1024 + c];
    }
    feat[b * 2048 + c] = mx;
    feat[b * 2048 + 1024 + c] = sm * (1.f / 1024.f);
}

// ---------------------------------------------------------------- FC head
__global__ __launch_bounds__(256) void k_fc1(const float* __restrict__ feat, const float* __restrict__ l1wT,
                                             const float* __restrict__ g6, const float* __restrict__ b6,
                                             float* __restrict__ f1) {
    int oc = blockIdx.x, b = blockIdx.y, t = threadIdx.x;
    __shared__ float fin[2048];
    __shared__ float psum[4][64];
    for (int u = t; u < 2048; u += 256) fin[u] = feat[b * 2048 + u];
    __syncthreads();
    int ol = t & 63, kc = t >> 6;
    int o = oc * 64 + ol;
    float acc = 0.f;
    for (int c = kc * 512; c < kc * 512 + 512; c++) acc += fin[c] * l1wT[(size_t)c * 512 + o];
    psum[kc][ol] = acc;
    __syncthreads();
    if (t < 64) {
        int oo = oc * 64 + t;
        float a = psum[0][t] + psum[1][t] + psum[2][t] + psum[3][t];
        float h = a * (g6[oo] * BN_SCALE) + b6[oo];
        f1[b * 512 + oo] = h >= 0.f ? h : 0.2f * h;
    }
}

__global__ __launch_bounds__(256) void k_fc2(const float* __restrict__ f1, const float* __restrict__ l2wT,
                                             const float* __restrict__ l2b,
                                             const float* __restrict__ g7, const float* __restrict__ b7,
                                             float* __restrict__ f2) {
    int b = blockIdx.x, t = threadIdx.x;
    __shared__ float fin[512];
    for (int u = t; u < 512; u += 256) fin[u] = f1[b * 512 + u];
    __syncthreads();
    if (t < 256) {
        int o = t;
        float acc = 0.f;
        for (int c = 0; c < 512; c++) acc += fin[c] * l2wT[(size_t)c * 256 + o];
        acc += l2b[o];
        float h = acc * (g7[o] * BN_SCALE) + b7[o];
        f2[b * 256 + o] = h >= 0.f ? h : 0.2f * h;
    }
}

__global__ __launch_bounds__(64) void k_fc3(const float* __restrict__ f2, const float* __restrict__ l3wT,
                                            const float* __restrict__ l3b,
                                            void* __restrict__ out, const int* __restrict__ flag) {
    int b = blockIdx.x, t = threadIdx.x;
    __shared__ float fin[256];
    for (int u = t; u < 256; u += 64) fin[u] = f2[b * 256 + u];
    __syncthreads();
    if (t < 40) {
        float acc = 0.f;
        for (int c = 0; c < 256; c++) acc += fin[c] * l3wT[(size_t)c * 40 + t];
        acc += l3b[t];
        if (*flag) ((__hip_bfloat16*)out)[b * 40 + t] = __float2bfloat16(acc);
        else       ((float*)out)[b * 40 + t] = acc;
    }
}

// ================================================================ host
extern "C" void kernel_launch(void* const* d_in, const int* in_sizes, int n_in,
                              void* d_out, int out_size, void* d_ws, size_t ws_size,
                              hipStream_t stream) {
    auto us = [&](int i) { return (const unsigned short*)d_in[i]; };

    float* ws = (float*)d_ws;
    size_t off = 0;
    auto A = [&](size_t n) { float* p = ws + off; off += (n + 3) & ~(size_t)3; return p; };
    auto AU = [&](size_t n) { return (unsigned short*)A((n + 1) / 2); };
    float* xf0  = A((size_t)BN_ * 3);
    float* x1   = A((size_t)BN_ * 64);
    float* x2   = A((size_t)BN_ * 64);
    float* x3   = A((size_t)BN_ * 128);
    float* x4   = A((size_t)BN_ * 256);
    float* h5   = A((size_t)BN_ * 1024);   // also pd scratch
    float* feat = A(8 * 2048);
    float* f1   = A(8 * 512);
    float* f2   = A(8 * 256);
    float* xx   = A(BN_);
    int*   idx  = (int*)A((size_t)BN_ * K_);
    int*   flag = (int*)A(4);
    float* qkvw = A((size_t)BN_ * 768);   // qkv / yz / knn-split scratch
    // bf16 activation copies
    unsigned short* xf0b = AU((size_t)BN_ * 3);
    unsigned short* x1b  = AU((size_t)BN_ * 64);
    unsigned short* x2b  = AU((size_t)BN_ * 64);
    unsigned short* x3b  = AU((size_t)BN_ * 128);
    unsigned short* x4b  = AU((size_t)BN_ * 256);
    unsigned short* owb  = AU((size_t)BN_ * 256);
    unsigned short* catb = AU((size_t)BN_ * 512);
    float* pmax = A(8 * 8 * 1024);
    float* psum = A(8 * 8 * 1024);
    // bf16 weights (n,k) layouts
    unsigned short* w1yzb = AU(128 * 3);
    unsigned short* w2yzb = AU(128 * 64);
    unsigned short* w3yzb = AU(256 * 64);
    unsigned short* w4yzb = AU(512 * 128);
    unsigned short* a1wib = AU(192 * 64);  unsigned short* a1wob = AU(64 * 64);
    unsigned short* a2wib = AU(192 * 64);  unsigned short* a2wob = AU(64 * 64);
    unsigned short* a3wib = AU(384 * 128); unsigned short* a3wob = AU(128 * 128);
    unsigned short* a4wib = AU(768 * 256); unsigned short* a4wob = AU(256 * 256);
    unsigned short* w5b   = AU(1024 * 512);
    // fp32 fc weights (transposed)
    float* l1wT  = A(2048 * 512);
    float* l2wT  = A(512 * 256);
    float* l3wT  = A(256 * 40);
    // converted vectors (fp32)
    float* g1f = A(64);   float* b1f = A(64);
    float* g2f = A(64);   float* b2f = A(64);
    float* g3f = A(128);  float* b3f = A(128);
    float* g4f = A(256);  float* b4f = A(256);
    float* bi1 = A(192);  float* bo1 = A(64);
    float* bi2 = A(192);  float* bo2 = A(64);
    float* bi3 = A(384);  float* bo3 = A(128);
    float* bi4 = A(768);  float* bo4 = A(256);
    float* g5f = A(1024); float* b5f = A(1024);
    float* g6f = A(512);  float* b6f = A(512);
    float* l2bf = A(256);
    float* g7f = A(256);  float* b7f = A(256);
    float* l3bf = A(40);

    // knn split buffers alias qkvw (dead during the kNN phase of each layer)
    unsigned short* xa = (unsigned short*)qkvw;
    unsigned short* xb = (unsigned short*)qkvw + (size_t)BN_ * 512;

    k_detect<<<1, 1, 0, stream>>>(us(2), us(5), us(8), us(11), us(30), us(33), us(37), flag);

    TList tl; int nb = 0; int k = 0;
    auto add = [&](int i, void* dst, int O, int I, int mode) {
        tl.p[k].src = d_in[i]; tl.p[k].dst = dst; tl.p[k].O = O; tl.p[k].I = I;
        tl.p[k].blk0 = nb; tl.p[k].mode = mode;
        nb += (O * I + 255) / 256; k++;
    };
    add(0,  xf0,   BN_ * 3, 1, 0);
    add(0,  xf0b,  BN_ * 3, 1, 2);
    add(1,  w1yzb, 64, 6, 3);
    add(4,  w2yzb, 64, 128, 3);
    add(7,  w3yzb, 128, 128, 3);
    add(10, w4yzb, 256, 256, 3);
    add(13, a1wib, 192, 64, 2);
    add(15, a1wob, 64, 64, 2);
    add(17, a2wib, 192, 64, 2);
    add(19, a2wob, 64, 64, 2);
    add(21, a3wib, 384, 128, 2);
    add(23, a3wob, 128, 128, 2);
    add(25, a4wib, 768, 256, 2);
    add(27, a4wob, 256, 256, 2);
    add(29, w5b,   1024, 512, 2);
    add(32, l1wT,  512, 2048, 0);
    add(35, l2wT,  256, 512, 0);
    add(39, l3wT,  40, 256, 0);
    add(2,  g1f, 64, 1, 0);   add(3,  b1f, 64, 1, 0);
    add(5,  g2f, 64, 1, 0);   add(6,  b2f, 64, 1, 0);
    add(8,  g3f, 128, 1, 0);  add(9,  b3f, 128, 1, 0);
    add(11, g4f, 256, 1, 0);  add(12, b4f, 256, 1, 0);
    add(14, bi1, 192, 1, 0);  add(16, bo1, 64, 1, 0);
    add(18, bi2, 192, 1, 0);  add(20, bo2, 64, 1, 0);
    add(22, bi3, 384, 1, 0);  add(24, bo3, 128, 1, 0);
    add(26, bi4, 768, 1, 0);  add(28, bo4, 256, 1, 0);
    add(30, g5f, 1024, 1, 0); add(31, b5f, 1024, 1, 0);
    add(33, g6f, 512, 1, 0);  add(34, b6f, 512, 1, 0);
    add(36, l2bf, 256, 1, 0);
    add(37, g7f, 256, 1, 0);  add(38, b7f, 256, 1, 0);
    add(40, l3bf, 40, 1, 0);
    k_prep<<<nb, 256, 0, stream>>>(tl, k, flag);

    float* yzb = qkvw;                 // fp32 yz scratch (after kNN phase)
    float* pd  = h5;                   // pd scratch (h5 dead until conv5)
    const dim3 pdmg(8, 8, 8);          // 128x128 tiles per batch

    // layer 1  (C=3 -> 64)
    k_norms<<<BN_ / 256, 256, 0, stream>>>(xf0, xx, 3);
    k_split<3, 32><<<(BN_ * 32) / 256, 256, 0, stream>>>(xf0, xa, xb);
    k_pdm<32><<<pdmg, 256, 0, stream>>>(xa, xb, xx, pd);
    k_sel<<<BN_ / 4, 256, 0, stream>>>(pd, idx);
    k_gemmb<3, 128, 64, 64><<<dim3(128, 2), 256, 0, stream>>>(xf0b, w1yzb, nullptr, nullptr, yzb, 0, 1.f, nullptr, nullptr, nullptr);
    k_edgemax<64><<<BN_ / 16, 256, 0, stream>>>(yzb, idx, g1f, b1f, x1, x1b);
    k_gemmb<64, 192, 64, 64><<<dim3(128, 3), 256, 0, stream>>>(x1b, a1wib, bi1, nullptr, qkvw, 64, 0.25f, nullptr, nullptr, nullptr);
    k_attn<64><<<N_, 256, 0, stream>>>(qkvw, owb);
    k_gemmb<64, 64, 64, 64><<<dim3(128, 1), 256, 0, stream>>>(owb, a1wob, bo1, x1, x1, 0, 1.f, nullptr, nullptr, x1b);

    // layer 2  (C=64 -> 64)
    k_norms<<<BN_ / 256, 256, 0, stream>>>(x1, xx, 64);
    k_split<64, 256><<<(BN_ * 256) / 256, 256, 0, stream>>>(x1, xa, xb);
    k_pdm<256><<<pdmg, 256, 0, stream>>>(xa, xb, xx, pd);
    k_sel<<<BN_ / 4, 256, 0, stream>>>(pd, idx);
    k_gemmb<64, 128, 64, 64><<<dim3(128, 2), 256, 0, stream>>>(x1b, w2yzb, nullptr, nullptr, yzb, 0, 1.f, nullptr, nullptr, nullptr);
    k_edgemax<64><<<BN_ / 16, 256, 0, stream>>>(yzb, idx, g2f, b2f, x2, x2b);
    k_gemmb<64, 192, 64, 64><<<dim3(128, 3), 256, 0, stream>>>(x2b, a2wib, bi2, nullptr, qkvw, 64, 0.25f, nullptr, nullptr, nullptr);
    k_attn<64><<<N_, 256, 0, stream>>>(qkvw, owb);
    k_gemmb<64, 64, 64, 64><<<dim3(128, 1), 256, 0, stream>>>(owb, a2wob, bo2, x2, x2, 0, 1.f, nullptr, nullptr, x2b);

    // layer 3  (C=64 -> 128)
    k_norms<<<BN_ / 256, 256, 0, stream>>>(x2, xx, 64);
    k_split<64, 256><<<(BN_ * 256) / 256, 256, 0, stream>>>(x2, xa, xb);
    k_pdm<256><<<pdmg, 256, 0, stream>>>(xa, xb, xx, pd);
    k_sel<<<BN_ / 4, 256, 0, stream>>>(pd, idx);
    k_gemmb<64, 256, 64, 64><<<dim3(128, 4), 256, 0, stream>>>(x2b, w3yzb, nullptr, nullptr, yzb, 0, 1.f, nullptr, nullptr, nullptr);
    k_edgemax<128><<<BN_ / 8, 256, 0, stream>>>(yzb, idx, g3f, b3f, x3, x3b);
    k_gemmb<128, 384, 64, 128><<<dim3(128, 3), 256, 0, stream>>>(x3b, a3wib, bi3, nullptr, qkvw, 128, 0.17677669529663687f, nullptr, nullptr, nullptr);
    k_attn<128><<<N_, 256, 0, stream>>>(qkvw, owb);
    k_gemmb<128, 128, 64, 64><<<dim3(128, 2), 256, 0, stream>>>(owb, a3wob, bo3, x3, x3, 0, 1.f, nullptr, nullptr, x3b);

    // layer 4  (C=128 -> 256)
    k_norms<<<BN_ / 256, 256, 0, stream>>>(x3, xx, 128);
    k_split<128, 512><<<(BN_ * 512) / 256, 256, 0, stream>>>(x3, xa, xb);
    k_pdm<512><<<pdmg, 256, 0, stream>>>(xa, xb, xx, pd);
    k_sel<<<BN_ / 4, 256, 0, stream>>>(pd, idx);
    k_gemmb<128, 512, 128, 128><<<dim3(64, 4), 256, 0, stream>>>(x3b, w4yzb, nullptr, nullptr, yzb, 0, 1.f, nullptr, nullptr, nullptr);
    k_edgemax<256><<<BN_ / 4, 256, 0, stream>>>(yzb, idx, g4f, b4f, x4, x4b);
    k_gemmb<256, 768, 128, 128><<<dim3(64, 6), 256, 0, stream>>>(x4b, a4wib, bi4, nullptr, qkvw, 256, 0.125f, nullptr, nullptr, nullptr);
    k_attn<256><<<N_, 256, 0, stream>>>(qkvw, owb);
    k_gemmb<256, 256, 64, 128><<<dim3(128, 2), 256, 0, stream>>>(owb, a4wob, bo4, x4, x4, 0, 1.f, nullptr, nullptr, x4b);

    // head
    k_cat<<<(BN_ * 512) / 256, 256, 0, stream>>>(x1b, x2b, x3b, x4b, catb);
    k_gemmb<512, 1024, 128, 128><<<dim3(64, 8), 256, 0, stream>>>(catb, w5b, nullptr, nullptr, h5, 0, 1.f, g5f, b5f, nullptr);
    k_pool1<<<dim3(4, 8, 8), 256, 0, stream>>>(h5, pmax, psum);
    k_pool2<<<dim3(4, 8), 256, 0, stream>>>(pmax, psum, feat);
    k_fc1<<<dim3(8, 8), 256, 0, stream>>>(feat, l1wT, g6f, b6f, f1);
    k_fc2<<<8, 256, 0, stream>>>(f1, l2wT, l2bf, g7f, b7f, f2);
    k_fc3<<<8, 64, 0, stream>>>(f2, l3wT, l3bf, d_out, flag);
}